// Round 17
// baseline (849.889 us; speedup 1.0000x reference)
//
#include <hip/hip_runtime.h>
#include <math.h>

constexpr int NB = 32;       // samples per angle
constexpr int LL = 16;       // bandwidth
constexpr int MM = 31;       // spectral orders (2*BW-1)
constexpr int MOFF = 15;
constexpr int NBATCH = 8;
constexpr int NCH = 50;
constexpr int NQ = MM * MM;          // 961
constexpr int SPAT = NB * NB * NB;   // 32768
constexpr long long HN = (long long)NBATCH * NCH * SPAT;  // 13,107,200

#define PI_D 3.14159265358979323846

__device__ inline float2 c_mk(float x, float y) { float2 r; r.x = x; r.y = y; return r; }

__device__ inline void fill_tw(float2* tw) {
  int t = threadIdx.x;
  if (t < 32) {
    double a = (double)t * (PI_D / 16.0);
    tw[t] = c_mk((float)cos(a), (float)sin(a));
  }
}

__device__ inline int bitrev5(int n) {
  return ((n & 1) << 4) | ((n & 2) << 2) | (n & 4) | ((n & 8) >> 2) | ((n & 16) >> 4);
}

__device__ inline double dpow(double x, int n) {
  double r = 1.0;
  for (int i = 0; i < n; ++i) r *= x;
  return r;
}

// ---------------- constants ----------------

__global__ void qw_kernel(float* __restrict__ qw) {
  int j = threadIdx.x;
  if (j >= NB) return;
  double beta = PI_D * (2 * j + 1) / 64.0;
  double acc = 0.0;
  for (int kk = 0; kk < LL; ++kk)
    acc += sin((double)(2 * j + 1) * (2 * kk + 1) * PI_D / 64.0) / (double)(2 * kk + 1);
  qw[j] = (float)((2.0 / 16.0) * sin(beta) * acc);
}

// out layout [j][l][mp][m]; eqmode: nj==1, beta=pi/2
__global__ void wigner_kernel(float* __restrict__ out, int nj, int eqmode) {
  __shared__ double fact[66];
  int tid = threadIdx.x;
  if (tid < 66) { double f = 1.0; for (int i = 2; i <= tid; ++i) f *= (double)i; fact[tid] = f; }
  __syncthreads();
  int total = nj * LL * NQ;
  int idx = blockIdx.x * blockDim.x + tid;
  if (idx >= total) return;
  int q = idx % NQ;
  int l = (idx / NQ) % LL;
  int j = idx / (NQ * LL);
  int mp = q / MM - MOFF;
  int m  = q % MM - MOFF;
  int amp = mp < 0 ? -mp : mp, am = m < 0 ? -m : m;
  float res = 0.f;
  if (amp <= l && am <= l) {
    double beta = eqmode ? (PI_D * 0.5) : (PI_D * (2 * j + 1) / 64.0);
    double c = cos(beta * 0.5), s = sin(beta * 0.5);
    double pref = sqrt(fact[l + mp] * fact[l - mp] * fact[l + m] * fact[l - m]);
    int k0 = max(0, m - mp), k1 = min(l + m, l - mp);
    double acc = 0.0;
    for (int k = k0; k <= k1; ++k) {
      double denom = fact[l + m - k] * fact[k] * fact[l - k - mp] * fact[k - m + mp];
      double term = dpow(c, 2 * l - 2 * k + m - mp) * dpow(s, 2 * k - m + mp) / denom;
      acc += ((mp - m + k) & 1) ? -term : term;
    }
    res = (float)(pref * acc);
  }
  out[idx] = res;
}

// dbT[j][l][n][m] = dbeta[j][l][m][n]
__global__ void transpose_d_kernel(const float* __restrict__ dbeta, float* __restrict__ dbT) {
  int idx = blockIdx.x * blockDim.x + threadIdx.x;
  if (idx >= NB * LL * NQ) return;
  int m = idx % MM;
  int n = (idx / MM) % MM;
  int jl = idx / NQ;
  dbT[idx] = dbeta[jl * NQ + m * MM + n];
}

// dbl[j][q][l] = qw[j] * dbeta[j][l][q]  (l contiguous, qw pre-folded)
__global__ void make_dbl_kernel(const float* __restrict__ dbeta, const float* __restrict__ qw,
                                float* __restrict__ dbl) {
  int idx = blockIdx.x * blockDim.x + threadIdx.x;
  if (idx >= NB * NQ * LL) return;
  int l = idx % LL;
  int q = (idx / LL) % NQ;
  int j = idx / (LL * NQ);
  dbl[idx] = qw[j] * dbeta[(j * LL + l) * NQ + q];
}

// ---------------- layer 1 (S2 conv) ----------------

__global__ __launch_bounds__(256) void s2_xh_kernel(const float* __restrict__ x,
                                                    const float* __restrict__ qw,
                                                    const float* __restrict__ dbeta,
                                                    float2* __restrict__ xh1) {
  __shared__ float xt[NB * NB];
  __shared__ float2 Xf0[NB * MM];
  __shared__ float2 tw[32];
  fill_tw(tw);
  int tid = threadIdx.x, b = blockIdx.x;
  for (int e = tid; e < NB * NB; e += 256) xt[e] = x[b * 1024 + e];
  __syncthreads();
  for (int e = tid; e < NB * MM; e += 256) {
    int j = e / MM, mi = e % MM, m = mi - MOFF;
    float re = 0.f, im = 0.f;
    const float* row = xt + j * NB;
    for (int a = 0; a < NB; ++a) {
      float v = row[a];
      float2 t = tw[(m * a) & 31];
      re += v * t.x; im -= v * t.y;   // e^{-i m a th}
    }
    Xf0[e] = c_mk(re, im);
  }
  __syncthreads();
  for (int e = tid; e < LL * MM; e += 256) {
    int l = e / MM, mi = e % MM;
    float re = 0.f, im = 0.f;
    for (int j = 0; j < NB; ++j) {
      float w = qw[j] * dbeta[(j * LL + l) * NQ + mi * MM + MOFF];
      float2 X = Xf0[j * MM + mi];
      re += w * X.x; im += w * X.y;
    }
    xh1[(b * LL + l) * MM + mi] = c_mk(re, im);
  }
}

// Wf[ni][ic] = sum_t W[ic][t] e^{-2pi i n t/32}, ic = i*Co+o
__global__ __launch_bounds__(256) void wfft_kernel(const float* __restrict__ W, int CiCo,
                                                   float2* __restrict__ Wf) {
  __shared__ float2 tw[32];
  fill_tw(tw);
  __syncthreads();
  int idx = blockIdx.x * blockDim.x + threadIdx.x;
  if (idx >= MM * CiCo) return;
  int ni = idx / CiCo, ic = idx % CiCo;
  int n = ni - MOFF;
  float re = 0.f, im = 0.f;
  for (int t = 0; t < NB; ++t) {
    float v = W[ic * NB + t];
    float2 tt = tw[(n * t) & 31];
    re += v * tt.x; im -= v * tt.y;
  }
  Wf[idx] = c_mk(re, im);
}

// z layout: [b][o][l][ni][mi].  z = deq0[l,ni] * xh1[b,l,mi] * conj(Wf1[ni,o])
__global__ void s2_z_kernel(const float2* __restrict__ xh1, const float2* __restrict__ Wf1,
                            const float* __restrict__ deq, float2* __restrict__ z) {
  int idx = blockIdx.x * blockDim.x + threadIdx.x;
  if (idx >= NBATCH * NCH * LL * NQ) return;
  int mi = idx % MM; int t = idx / MM;
  int ni = t % MM; t /= MM;
  int l = t % LL; t /= LL;
  int o = t % NCH; int b = t / NCH;
  float d0 = deq[(l * MM + ni) * MM + MOFF];
  float2 xv = xh1[(b * LL + l) * MM + mi];
  float2 wv = Wf1[ni * NCH + o];
  float re = d0 * (xv.x * wv.x + xv.y * wv.y);
  float im = d0 * (xv.y * wv.x - xv.x * wv.y);
  z[idx] = c_mk(re, im);
}

// ---------------- SO(3) inverse transform: split into fjq + dft ----------------

// F[bo][j][q] = sum_l (2l+1) * d^l_{m,n}(beta_j) * z[bo][l][q], q = ni*31+mi.
__global__ __launch_bounds__(256) void fjq_kernel(const float2* __restrict__ z,
                                                  const float* __restrict__ dbT,
                                                  float2* __restrict__ F) {
  __shared__ float2 zs[2][LL][8];
  int qg = blockIdx.x % 121;
  int bg = blockIdx.x / 121;
  int tid = threadIdx.x;
  int j = tid >> 3, ql = tid & 7;
  int q = qg * 8 + ql;
  bool qok = q < NQ;
  int qc = qok ? q : NQ - 1;
  float w[LL];
  #pragma unroll
  for (int l = 0; l < LL; ++l)
    w[l] = (2.f * l + 1.f) * dbT[(j * LL + l) * NQ + qc];
  int bo0 = bg * 25;
  if (tid < 128) {
    int l = tid >> 3, qq = qg * 8 + (tid & 7);
    int dd = (qq < NQ) ? (qq / MM - MOFF) : 99; if (dd < 0) dd = -dd;
    zs[0][l][tid & 7] = (l >= dd) ? z[((long long)bo0 * LL + l) * NQ + qq] : c_mk(0.f, 0.f);
  }
  __syncthreads();
  for (int i = 0; i < 25; ++i) {
    int bo = bo0 + i;
    if (i < 24 && tid < 128) {
      int l = tid >> 3, qq = qg * 8 + (tid & 7);
      int dd = (qq < NQ) ? (qq / MM - MOFF) : 99; if (dd < 0) dd = -dd;
      zs[(i + 1) & 1][l][tid & 7] =
          (l >= dd) ? z[((long long)(bo + 1) * LL + l) * NQ + qq] : c_mk(0.f, 0.f);
    }
    float fr = 0.f, fi = 0.f;
    #pragma unroll
    for (int l = 0; l < LL; ++l) {
      float2 zv = zs[i & 1][l][ql];
      fr += w[l] * zv.x; fi += w[l] * zv.y;
    }
    if (qok) F[((long long)bo * NB + j) * NQ + q] = c_mk(fr, fi);
    __syncthreads();
  }
}

// 2 tiles per 64-thread block. Direct coalesced register loads of F, register
// radix-2 FFTs, single-plane LDS transpose -> 8.7KB LDS.
__global__ __launch_bounds__(64) void so3_dft_kernel(const float2* __restrict__ F,
                                                     const float* __restrict__ bias,
                                                     float* __restrict__ out,
                                                     float2* __restrict__ parts) {
  __shared__ float S[2][32][33];
  __shared__ float2 tw[32];
  fill_tw(tw);
  int tid = threadIdx.x;
  int lane = tid & 31;
  int t = tid >> 5;                 // tile within block
  int idx = blockIdx.x * 2 + t;     // global tile
  int j = idx & 31;
  int bo = idx >> 5;                // same for both tiles (2 | 32)
  int o = bo % NCH;
  __syncthreads();                  // tw ready

  float vr[32], vi[32];

  // direct register load: lane = km; mi = (lane+15)&31 (lane 16 -> bin 16 = 0)
  int mi = (lane + 15) & 31;
  const float2* src = F + ((long long)bo * NB + j) * NQ + mi;
  bool mok = mi < MM;
  #pragma unroll
  for (int kn = 0; kn < 32; ++kn) {
    const int ni = (kn + 15) & 31;
    if (ni < MM) {
      float2 v = mok ? src[ni * MM] : c_mk(0.f, 0.f);
      vr[kn] = v.x; vi[kn] = v.y;
    } else { vr[kn] = 0.f; vi[kn] = 0.f; }
  }

  // ---- dim0 FFT over kn (registers), +i sign
  #pragma unroll
  for (int st = 0; st < 5; ++st) {
    const int half = 16 >> st, tmul = 1 << st;
    #pragma unroll
    for (int p = 0; p < 16; ++p) {
      const int j2 = p & (half - 1);
      const int i0 = ((p >> (4 - st)) << (5 - st)) + j2;
      const int i1 = i0 + half;
      float2 tt = tw[(j2 * tmul) & 31];
      float ur = vr[i0], ui = vi[i0], wr = vr[i1], wi = vi[i1];
      float dr = ur - wr, di = ui - wi;
      vr[i0] = ur + wr; vi[i0] = ui + wi;
      vr[i1] = dr * tt.x - di * tt.y;
      vi[i1] = dr * tt.y + di * tt.x;
    }
  }

  // ---- transpose via single plane: re, then im
  #pragma unroll
  for (int g = 0; g < 32; ++g) S[t][g][lane] = vr[bitrev5(g)];
  __syncthreads();
  #pragma unroll
  for (int k = 0; k < 32; ++k) vr[k] = S[t][lane][k];
  __syncthreads();
  #pragma unroll
  for (int g = 0; g < 32; ++g) S[t][g][lane] = vi[bitrev5(g)];
  __syncthreads();
  #pragma unroll
  for (int k = 0; k < 32; ++k) vi[k] = S[t][lane][k];

  // ---- dim1 FFT over km (registers), +i sign; lane = g now
  #pragma unroll
  for (int st = 0; st < 5; ++st) {
    const int half = 16 >> st, tmul = 1 << st;
    #pragma unroll
    for (int p = 0; p < 16; ++p) {
      const int j2 = p & (half - 1);
      const int i0 = ((p >> (4 - st)) << (5 - st)) + j2;
      const int i1 = i0 + half;
      float2 tt = tw[(j2 * tmul) & 31];
      float ur = vr[i0], ui = vi[i0], wr = vr[i1], wi = vi[i1];
      float dr = ur - wr, di = ui - wi;
      vr[i0] = ur + wr; vi[i0] = ui + wi;
      vr[i1] = dr * tt.x - di * tt.y;
      vi[i1] = dr * tt.y + di * tt.x;
    }
  }

  // ---- store out[a,g] = Re X[a] + bias (g = lane, coalesced); fused bn stats
  float bval = bias[o];
  long long obase = (long long)bo * SPAT + (long long)j * 1024 + lane;
  float s1 = 0.f, s2 = 0.f;
  #pragma unroll
  for (int a = 0; a < 32; ++a) {
    float val = vr[bitrev5(a)] + bval;
    out[obase + a * 32] = val;
    s1 += val; s2 += val * val;
  }
  #pragma unroll
  for (int off = 32; off > 0; off >>= 1) {
    s1 += __shfl_down(s1, off);
    s2 += __shfl_down(s2, off);
  }
  if (tid == 0) {
    atomicAdd(&parts[bo].x, s1);
    atomicAdd(&parts[bo].y, s2);
  }
}

// ---------------- batchnorm ----------------

__global__ void bn_finalize_kernel(const float2* __restrict__ partials,
                                   const float* __restrict__ g, const float* __restrict__ bb,
                                   float2* __restrict__ sc) {
  int o = threadIdx.x;
  if (o >= NCH) return;
  float s = 0.f, ss = 0.f;
  for (int b = 0; b < NBATCH; ++b) { float2 p = partials[b * NCH + o]; s += p.x; ss += p.y; }
  float inv = 1.f / (float)(NBATCH * SPAT);
  float mu = s * inv;
  float var = ss * inv - mu * mu;
  float scale = g[o] * rsqrtf(var + 1e-5f);
  sc[o] = c_mk(scale, bb[o] - mu * scale);
}

// ---------------- SO(3) conv ----------------

// Forward 2D FFT of a real 32x32 tile; 2 tiles per 64-thread block.
__global__ __launch_bounds__(64) void dft2f_kernel(const float* __restrict__ h,
                                                   const float2* __restrict__ sc,
                                                   float2* __restrict__ Xf) {
  __shared__ float S[2][32][33];
  __shared__ float2 tw[32];
  fill_tw(tw);
  int tid = threadIdx.x;
  int lane = tid & 31;
  int t = tid >> 5;
  long long idx = blockIdx.x * 2 + t;
  int c = (int)((idx >> 5) % NCH);
  float2 s = sc[c];
  __syncthreads();                  // tw ready

  float vr[32], vi[32];

  // lane = a row: load 32 consecutive floats (L1-friendly), bn+relu
  const float4* hp = reinterpret_cast<const float4*>(h + idx * 1024 + lane * 32);
  #pragma unroll
  for (int q4 = 0; q4 < 8; ++q4) {
    float4 v = hp[q4];
    vr[q4 * 4 + 0] = fmaxf(v.x * s.x + s.y, 0.f);
    vr[q4 * 4 + 1] = fmaxf(v.y * s.x + s.y, 0.f);
    vr[q4 * 4 + 2] = fmaxf(v.z * s.x + s.y, 0.f);
    vr[q4 * 4 + 3] = fmaxf(v.w * s.x + s.y, 0.f);
    vi[q4 * 4 + 0] = 0.f; vi[q4 * 4 + 1] = 0.f;
    vi[q4 * 4 + 2] = 0.f; vi[q4 * 4 + 3] = 0.f;
  }

  // ---- FFT over g (registers), conj twiddles (e^{-i})
  #pragma unroll
  for (int st = 0; st < 5; ++st) {
    const int half = 16 >> st, tmul = 1 << st;
    #pragma unroll
    for (int p = 0; p < 16; ++p) {
      const int j2 = p & (half - 1);
      const int i0 = ((p >> (4 - st)) << (5 - st)) + j2;
      const int i1 = i0 + half;
      float2 tt = tw[(j2 * tmul) & 31];
      float ur = vr[i0], ui = vi[i0], wr = vr[i1], wi = vi[i1];
      float dr = ur - wr, di = ui - wi;
      vr[i0] = ur + wr; vi[i0] = ui + wi;
      vr[i1] = dr * tt.x + di * tt.y;     // conj twiddle
      vi[i1] = di * tt.x - dr * tt.y;
    }
  }

  // ---- transpose via single plane: re, then im (un-bit-reversed rows)
  #pragma unroll
  for (int k = 0; k < 32; ++k) S[t][k][lane] = vr[bitrev5(k)];
  __syncthreads();
  #pragma unroll
  for (int a = 0; a < 32; ++a) vr[a] = S[t][lane][a];
  __syncthreads();
  #pragma unroll
  for (int k = 0; k < 32; ++k) S[t][k][lane] = vi[bitrev5(k)];
  __syncthreads();
  #pragma unroll
  for (int a = 0; a < 32; ++a) vi[a] = S[t][lane][a];

  // ---- FFT over a (registers), conj twiddles; lane = k_n now
  #pragma unroll
  for (int st = 0; st < 5; ++st) {
    const int half = 16 >> st, tmul = 1 << st;
    #pragma unroll
    for (int p = 0; p < 16; ++p) {
      const int j2 = p & (half - 1);
      const int i0 = ((p >> (4 - st)) << (5 - st)) + j2;
      const int i1 = i0 + half;
      float2 tt = tw[(j2 * tmul) & 31];
      float ur = vr[i0], ui = vi[i0], wr = vr[i1], wi = vi[i1];
      float dr = ur - wr, di = ui - wi;
      vr[i0] = ur + wr; vi[i0] = ui + wi;
      vr[i1] = dr * tt.x + di * tt.y;
      vi[i1] = di * tt.x - dr * tt.y;
    }
  }

  // ---- store: lane holds X[m, n] for all m at bin k_n = lane.
  int ni = (lane + 15) & 31;
  if (ni < MM) {
    float2* dst = Xf + idx * NQ + ni;
    #pragma unroll
    for (int mi = 0; mi < MM; ++mi) {
      const int km = (mi + 17) & 31;
      dst[mi * MM] = c_mk(vr[bitrev5(km)], vi[bitrev5(km)]);
    }
  }
}

// xh[bc,l,q] = sum_j dbl[j,q,l]*Xf[bc,j,q].  Block = 16 bc x 16 q; the block's
// dbl slice (32j x 16q x 16l = 32KB) is staged in LDS once and shared by the
// 16 bc (cuts redundant dbl traffic 16x; was the L2-BW limiter).
// LDS layout [j][l4][q] float4: wave reads 16 distinct 16B addrs -> <=2-way.
__global__ __launch_bounds__(256) void xh_kernel(const float2* __restrict__ Xf,
                                                 const float* __restrict__ dbl,
                                                 float2* __restrict__ xh) {
  __shared__ __align__(16) float4 dblS[NB * 4 * 16];   // 32 KB
  int tile = blockIdx.x % 61;        // q-tile (16 q each; 61*16 >= 961)
  int grp  = blockIdx.x / 61;        // bc-group (16 bc each; 25 groups)
  int tid = threadIdx.x;
  int ql = tid & 15;                 // q_local
  int bl = tid >> 4;                 // bc_local
  int q0 = tile * 16;
  int q = q0 + ql;
  bool qok = q < NQ;
  int bc = grp * 16 + bl;

  // stage dbl slice: 2048 float4s, 8 per thread, coalesced.
  {
    const float4* src = reinterpret_cast<const float4*>(dbl);
    #pragma unroll
    for (int k = 0; k < 8; ++k) {
      int e = k * 256 + tid;               // [j][q][l4]
      int l4 = e & 3;
      int qq = (e >> 2) & 15;
      int j = e >> 6;
      int qg = q0 + qq; if (qg >= NQ) qg = NQ - 1;
      dblS[(j * 4 + l4) * 16 + qq] = src[((long long)j * NQ + qg) * 4 + l4];
    }
  }
  __syncthreads();

  int dm = q / MM - MOFF; if (dm < 0) dm = -dm;
  int dn = q % MM - MOFF; if (dn < 0) dn = -dn;
  int lmin = dm > dn ? dm : dn;

  float2 acc[LL];
  #pragma unroll
  for (int l = 0; l < LL; ++l) acc[l] = c_mk(0.f, 0.f);

  const float2* xbase = Xf + (long long)bc * NB * NQ + q;
  for (int j = 0; j < NB; ++j) {
    float2 xv = qok ? xbase[(long long)j * NQ] : c_mk(0.f, 0.f);
    float4 w0 = dblS[(j * 4 + 0) * 16 + ql];
    float4 w1 = dblS[(j * 4 + 1) * 16 + ql];
    float4 w2 = dblS[(j * 4 + 2) * 16 + ql];
    float4 w3 = dblS[(j * 4 + 3) * 16 + ql];
    float wv[16] = {w0.x, w0.y, w0.z, w0.w, w1.x, w1.y, w1.z, w1.w,
                    w2.x, w2.y, w2.z, w2.w, w3.x, w3.y, w3.z, w3.w};
    #pragma unroll
    for (int l = 0; l < LL; ++l) {
      acc[l].x += wv[l] * xv.x;
      acc[l].y += wv[l] * xv.y;
    }
  }
  if (qok) {
    #pragma unroll
    for (int l = 0; l < LL; ++l)
      if (l >= lmin) xh[((long long)bc * LL + l) * NQ + q] = acc[l];
  }
}

// hk2[r][ni][ich], r = (l*8+b)*31+mi (l-major). Support sparsity.
__global__ __launch_bounds__(64) void hk_kernel(const float2* __restrict__ xh,
                                                const float* __restrict__ deq,
                                                float2* __restrict__ hk2) {
  int r = blockIdx.x;                 // (l*8+b)*31 + mi
  int mi = r % MM;
  int lb = r / MM;                    // l*8 + b
  int b = lb & 7;
  int l = lb >> 3;
  int adm = mi - MOFF; adm = adm < 0 ? -adm : adm;
  if (adm > l) return;
  int ich = threadIdx.x;
  if (ich >= NCH) return;
  float2 row[MM];
  const float2* src = xh + ((long long)(b * NCH + ich) * LL + l) * NQ + mi * MM;
  #pragma unroll
  for (int k = 0; k < MM; ++k) row[k] = src[k];
  const float* dl = deq + l * NQ;
  long long obase = (long long)r * MM * NCH + ich;
  for (int ni = MOFF - l; ni <= MOFF + l; ++ni) {
    const float* dr = dl + ni * MM;
    float re = 0.f, im = 0.f;
    #pragma unroll
    for (int k = 0; k < MM; ++k) {
      float d = dr[k];
      re += d * row[k].x;
      im += d * row[k].y;
    }
    hk2[obase + (long long)ni * NCH] = c_mk(re, im);
  }
}

// z[b][o][l][ni][mi] = sum_i hk2[(r*31+ni)*50+i] * conj(Wf[ni,i,o]).
__global__ __launch_bounds__(256) void z_kernel(const float2* __restrict__ hk2,
                                                const float2* __restrict__ Wf,
                                                float2* __restrict__ z) {
  __shared__ float2 ws[NCH * NCH];   // 20 KB
  int blk = blockIdx.x;
  int ni = 0;
  for (;;) {
    int d = ni - MOFF; if (d < 0) d = -d;
    int nt = 32 - 2 * d;
    if (blk < nt) break;
    blk -= nt; ++ni;
  }
  int dmin = ni - MOFF; if (dmin < 0) dmin = -dmin;
  int tid = threadIdx.x;
  {
    const float4* s4 = reinterpret_cast<const float4*>(Wf + ni * (NCH * NCH));
    float4* d4 = reinterpret_cast<float4*>(ws);
    for (int e = tid; e < NCH * NCH / 2; e += 256) d4[e] = s4[e];
  }
  __syncthreads();
  if (tid >= 248) return;
  int r = dmin * 248 + blk * 124 + (tid % 124);
  int o0 = (tid / 124) * 25;
  int mi = r % MM;
  int rem = r / MM;                  // l*8 + b
  int b = rem & 7;
  int l = rem >> 3;

  const float4* h4 = reinterpret_cast<const float4*>(hk2 + ((long long)r * MM + ni) * NCH);

  float2 acc[25];
  #pragma unroll
  for (int u = 0; u < 25; ++u) acc[u] = c_mk(0.f, 0.f);

  for (int ih = 0; ih < 25; ++ih) {     // 2 channels per iteration
    float4 hv = h4[ih];
    const float2* w0 = ws + (2 * ih) * NCH + o0;
    #pragma unroll
    for (int u = 0; u < 25; ++u) {
      float2 w = w0[u];
      acc[u].x += hv.x * w.x + hv.y * w.y;
      acc[u].y += hv.y * w.x - hv.x * w.y;
    }
    const float2* w1 = w0 + NCH;
    #pragma unroll
    for (int u = 0; u < 25; ++u) {
      float2 w = w1[u];
      acc[u].x += hv.z * w.x + hv.w * w.y;
      acc[u].y += hv.w * w.x - hv.z * w.y;
    }
  }

  long long zbase = (((long long)(b * NCH + o0) * LL + l) * NQ) + ni * MM + mi;
  #pragma unroll
  for (int u = 0; u < 25; ++u)
    z[zbase + (long long)u * LL * NQ] = acc[u];
}

// ---------------- head ----------------

// pool with fused bn+relu (layer-3 scale/shift applied per element)
__global__ void pool_kernel(const float* __restrict__ h, const float2* __restrict__ sc,
                            float* __restrict__ pooled) {
  __shared__ float sm[256];
  int tid = threadIdx.x;
  int o = blockIdx.x % NCH;
  float2 s = sc[o];
  const float* base = h + (long long)blockIdx.x * SPAT;
  float best = -1e30f;
  for (int e = tid; e < 1024; e += 256) {
    float acc = 0.f;
    for (int g = 0; g < NB; ++g) {
      float v = base[e * NB + g];
      acc += fmaxf(v * s.x + s.y, 0.f);
    }
    best = fmaxf(best, acc * (1.f / 32.f));
  }
  sm[tid] = best;
  __syncthreads();
  for (int st = 128; st > 0; st >>= 1) {
    if (tid < st) sm[tid] = fmaxf(sm[tid], sm[tid + st]);
    __syncthreads();
  }
  if (tid == 0) pooled[blockIdx.x] = sm[0];
}

// fc1 + BN1 + relu. Thread = output o (8 blocks x 32).
__global__ __launch_bounds__(32) void fc1_kernel(const float* __restrict__ pooled,
    const float* __restrict__ fc1w, const float* __restrict__ fc1b,
    const float* __restrict__ g1, const float* __restrict__ b1,
    float* __restrict__ A) {
  int o = blockIdx.x * 32 + threadIdx.x;   // 0..255
  const float* wr = fc1w + o * NCH;
  float v[NBATCH];
  float bias = fc1b[o];
  #pragma unroll
  for (int b = 0; b < NBATCH; ++b) v[b] = bias;
  for (int c = 0; c < NCH; ++c) {
    float w = wr[c];
    #pragma unroll
    for (int b = 0; b < NBATCH; ++b) v[b] += pooled[b * NCH + c] * w;
  }
  float s = 0.f, ss = 0.f;
  #pragma unroll
  for (int b = 0; b < NBATCH; ++b) { s += v[b]; ss += v[b] * v[b]; }
  float mu = s * 0.125f, var = ss * 0.125f - mu * mu;
  float scl = g1[o] * rsqrtf(var + 1e-5f), sh = b1[o] - mu * scl;
  #pragma unroll
  for (int b = 0; b < NBATCH; ++b) A[b * 256 + o] = fmaxf(v[b] * scl + sh, 0.f);
}

// fc2 + BN2 + relu. 16 blocks x 64; thread = (o_local, b).
__global__ __launch_bounds__(64) void fc2_kernel(const float* __restrict__ A,
    const float* __restrict__ fc2w, const float* __restrict__ fc2b,
    const float* __restrict__ g2, const float* __restrict__ b2,
    float* __restrict__ A2) {
  int tid = threadIdx.x;
  int o = blockIdx.x * 8 + (tid >> 3);
  int b = tid & 7;
  const float4* av = reinterpret_cast<const float4*>(A + b * 256);
  const float4* wv = reinterpret_cast<const float4*>(fc2w + o * 256);
  float acc = fc2b[o];
  #pragma unroll
  for (int c4 = 0; c4 < 64; ++c4) {
    float4 a = av[c4], w = wv[c4];
    acc += a.x * w.x + a.y * w.y + a.z * w.z + a.w * w.w;
  }
  float s = acc, ss = acc * acc;
  #pragma unroll
  for (int m = 1; m < 8; m <<= 1) {
    s += __shfl_xor(s, m);
    ss += __shfl_xor(ss, m);
  }
  float mu = s * 0.125f, var = ss * 0.125f - mu * mu;
  float scl = g2[o] * rsqrtf(var + 1e-5f), sh = b2[o] - mu * scl;
  A2[b * 128 + o] = fmaxf(acc * scl + sh, 0.f);
}

// fc3 + log-softmax. One block per batch.
__global__ __launch_bounds__(64) void fc3_kernel(const float* __restrict__ A2,
    const float* __restrict__ fc3w, const float* __restrict__ fc3b,
    float* __restrict__ out) {
  __shared__ float Cm[40];
  int tid = threadIdx.x;
  int b = blockIdx.x;
  if (tid < 40) {
    const float* wr = fc3w + tid * 128;
    const float* ar = A2 + b * 128;
    float acc = fc3b[tid];
    #pragma unroll
    for (int c = 0; c < 128; ++c) acc += ar[c] * wr[c];
    Cm[tid] = acc;
  }
  __syncthreads();
  if (tid == 0) {
    float mx = -1e30f;
    for (int f = 0; f < 40; ++f) mx = fmaxf(mx, Cm[f]);
    float se = 0.f;
    for (int f = 0; f < 40; ++f) se += expf(Cm[f] - mx);
    float lse = mx + logf(se);
    for (int f = 0; f < 40; ++f) out[b * 40 + f] = Cm[f] - lse;
  }
}

// ---------------- host ----------------

extern "C" void kernel_launch(void* const* d_in, const int* in_sizes, int n_in,
                              void* d_out, int out_size, void* d_ws, size_t ws_size,
                              hipStream_t stream) {
  (void)in_sizes; (void)n_in; (void)out_size;
  const float* x    = (const float*)d_in[0];
  const float* k1   = (const float*)d_in[1];
  const float* c1b  = (const float*)d_in[2];
  const float* bn1g = (const float*)d_in[3];
  const float* bn1b = (const float*)d_in[4];
  const float* k2   = (const float*)d_in[5];
  const float* c2b  = (const float*)d_in[6];
  const float* bn2g = (const float*)d_in[7];
  const float* bn2b = (const float*)d_in[8];
  const float* k3   = (const float*)d_in[9];
  const float* c3b  = (const float*)d_in[10];
  const float* bn3g = (const float*)d_in[11];
  const float* bn3b = (const float*)d_in[12];
  const float* fc1w = (const float*)d_in[13];
  const float* fc1b = (const float*)d_in[14];
  const float* g1   = (const float*)d_in[15];
  const float* bb1  = (const float*)d_in[16];
  const float* fc2w = (const float*)d_in[17];
  const float* fc2b = (const float*)d_in[18];
  const float* g2   = (const float*)d_in[19];
  const float* bb2  = (const float*)d_in[20];
  const float* fc3w = (const float*)d_in[21];
  const float* fc3b = (const float*)d_in[22];
  float* out = (float*)d_out;

  char* ws = (char*)d_ws;
  size_t off = 0;
  auto alloc = [&](size_t n) -> char* {
    char* p = ws + off;
    off += (n + 255) & ~(size_t)255;
    return p;
  };

  float*  dbeta  = (float*)alloc(sizeof(float) * NB * LL * NQ);      // 1.97 MB
  float*  dbT    = (float*)alloc(sizeof(float) * NB * LL * NQ);      // 1.97 MB
  float*  dbl    = (float*)alloc(sizeof(float) * NB * NQ * LL);      // 1.97 MB
  float*  deq    = (float*)alloc(sizeof(float) * LL * NQ);
  float*  qw     = (float*)alloc(sizeof(float) * NB);
  float2* xh1    = (float2*)alloc(sizeof(float2) * NBATCH * LL * MM);
  float2* Wf     = (float2*)alloc(sizeof(float2) * MM * NCH * NCH);  // 620 KB
  float2* parts  = (float2*)alloc(sizeof(float2) * NBATCH * NCH);
  float2* bnsc   = (float2*)alloc(sizeof(float2) * 64);
  float*  pooled = (float*)alloc(sizeof(float) * NBATCH * NCH);
  float*  Abuf   = (float*)alloc(sizeof(float) * NBATCH * 256);
  float*  A2buf  = (float*)alloc(sizeof(float) * NBATCH * 128);
  float*  HA     = (float*)alloc(sizeof(float) * (size_t)HN);        // 52.4 MB
  float*  HB     = (float*)alloc(sizeof(float) * (size_t)HN);        // 52.4 MB
  size_t XFB = (size_t)NBATCH * NCH * NB * NQ * sizeof(float2);      // 98.4 MB
  size_t XHB = (size_t)NBATCH * NCH * LL * NQ * sizeof(float2);      // 49.2 MB
  char* AR = alloc(XFB + XHB);                                       // 147.6 MB arena
  float2* Xf  = (float2*)AR;           // live: dft2 -> xh
  float2* xh  = (float2*)(AR + XFB);   // live: xh -> hk
  float2* hk2 = (float2*)AR;           // live: hk -> z    (reuses dead Xf)
  float2* zb  = (float2*)(AR + XFB);   // live: z -> fjq   (reuses dead xh; also z1)
  float2* Fb  = (float2*)AR;           // live: fjq -> dft (reuses dead hk2/Xf; 98.4 MB exact)

  if (ws_size < off) return;  // insufficient scratch: leave d_out zeroed

  const int T = 256;
  const size_t PARTS_B = sizeof(float2) * NBATCH * NCH;
  // constants
  qw_kernel<<<1, 32, 0, stream>>>(qw);
  wigner_kernel<<<(NB * LL * NQ + T - 1) / T, T, 0, stream>>>(dbeta, NB, 0);
  wigner_kernel<<<(LL * NQ + T - 1) / T, T, 0, stream>>>(deq, 1, 1);
  transpose_d_kernel<<<(NB * LL * NQ + T - 1) / T, T, 0, stream>>>(dbeta, dbT);
  make_dbl_kernel<<<(NB * NQ * LL + T - 1) / T, T, 0, stream>>>(dbeta, qw, dbl);

  // ---- layer 1: S2 conv -> HA
  s2_xh_kernel<<<NBATCH, T, 0, stream>>>(x, qw, dbeta, xh1);
  wfft_kernel<<<(MM * 1 * NCH + T - 1) / T, T, 0, stream>>>(k1, 1 * NCH, Wf);
  s2_z_kernel<<<(NBATCH * NCH * LL * NQ + T - 1) / T, T, 0, stream>>>(xh1, Wf, deq, zb);
  fjq_kernel<<<121 * 16, T, 0, stream>>>(zb, dbT, Fb);
  hipMemsetAsync(parts, 0, PARTS_B, stream);
  so3_dft_kernel<<<NBATCH * NCH * NB / 2, 64, 0, stream>>>(Fb, c1b, HA, parts);
  bn_finalize_kernel<<<1, 64, 0, stream>>>(parts, bn1g, bn1b, bnsc);

  // ---- layer 2: SO(3) conv HA -> HB (bn1+relu fused into dft2f load)
  dft2f_kernel<<<NBATCH * NCH * NB / 2, 64, 0, stream>>>(HA, bnsc, Xf);
  xh_kernel<<<61 * 25, T, 0, stream>>>(Xf, dbl, xh);
  wfft_kernel<<<(MM * NCH * NCH + T - 1) / T, T, 0, stream>>>(k2, NCH * NCH, Wf);
  hk_kernel<<<NBATCH * LL * MM, 64, 0, stream>>>(xh, deq, hk2);
  z_kernel<<<512, T, 0, stream>>>(hk2, Wf, zb);
  fjq_kernel<<<121 * 16, T, 0, stream>>>(zb, dbT, Fb);
  hipMemsetAsync(parts, 0, PARTS_B, stream);
  so3_dft_kernel<<<NBATCH * NCH * NB / 2, 64, 0, stream>>>(Fb, c2b, HB, parts);
  bn_finalize_kernel<<<1, 64, 0, stream>>>(parts, bn2g, bn2b, bnsc);

  // ---- layer 3: SO(3) conv HB -> HA (bn2+relu fused into dft2f load)
  dft2f_kernel<<<NBATCH * NCH * NB / 2, 64, 0, stream>>>(HB, bnsc, Xf);
  xh_kernel<<<61 * 25, T, 0, stream>>>(Xf, dbl, xh);
  wfft_kernel<<<(MM * NCH * NCH + T - 1) / T, T, 0, stream>>>(k3, NCH * NCH, Wf);
  hk_kernel<<<NBATCH * LL * MM, 64, 0, stream>>>(xh, deq, hk2);
  z_kernel<<<512, T, 0, stream>>>(hk2, Wf, zb);
  fjq_kernel<<<121 * 16, T, 0, stream>>>(zb, dbT, Fb);
  hipMemsetAsync(parts, 0, PARTS_B, stream);
  so3_dft_kernel<<<NBATCH * NCH * NB / 2, 64, 0, stream>>>(Fb, c3b, HA, parts);
  bn_finalize_kernel<<<1, 64, 0, stream>>>(parts, bn3g, bn3b, bnsc);

  // ---- head: pool (bn3+relu fused) + split FC stack
  pool_kernel<<<NBATCH * NCH, T, 0, stream>>>(HA, bnsc, pooled);
  fc1_kernel<<<8, 32, 0, stream>>>(pooled, fc1w, fc1b, g1, bb1, Abuf);
  fc2_kernel<<<16, 64, 0, stream>>>(Abuf, fc2w, fc2b, g2, bb2, A2buf);
  fc3_kernel<<<8, 64, 0, stream>>>(A2buf, fc3w, fc3b, out);
}

// Round 18
// 681.511 us; speedup vs baseline: 1.2471x; 1.2471x over previous
//
#include <hip/hip_runtime.h>
#include <math.h>

constexpr int NB = 32;       // samples per angle
constexpr int LL = 16;       // bandwidth
constexpr int MM = 31;       // spectral orders (2*BW-1)
constexpr int MOFF = 15;
constexpr int NBATCH = 8;
constexpr int NCH = 50;
constexpr int NQ = MM * MM;          // 961
constexpr int SPAT = NB * NB * NB;   // 32768
constexpr long long HN = (long long)NBATCH * NCH * SPAT;  // 13,107,200

#define PI_D 3.14159265358979323846

__device__ inline float2 c_mk(float x, float y) { float2 r; r.x = x; r.y = y; return r; }

__device__ inline void fill_tw(float2* tw) {
  int t = threadIdx.x;
  if (t < 32) {
    double a = (double)t * (PI_D / 16.0);
    tw[t] = c_mk((float)cos(a), (float)sin(a));
  }
}

__device__ inline int bitrev5(int n) {
  return ((n & 1) << 4) | ((n & 2) << 2) | (n & 4) | ((n & 8) >> 2) | ((n & 16) >> 4);
}

__device__ inline double dpow(double x, int n) {
  double r = 1.0;
  for (int i = 0; i < n; ++i) r *= x;
  return r;
}

// ---------------- constants ----------------

__global__ void qw_kernel(float* __restrict__ qw) {
  int j = threadIdx.x;
  if (j >= NB) return;
  double beta = PI_D * (2 * j + 1) / 64.0;
  double acc = 0.0;
  for (int kk = 0; kk < LL; ++kk)
    acc += sin((double)(2 * j + 1) * (2 * kk + 1) * PI_D / 64.0) / (double)(2 * kk + 1);
  qw[j] = (float)((2.0 / 16.0) * sin(beta) * acc);
}

// out layout [j][l][mp][m]; eqmode: nj==1, beta=pi/2
__global__ void wigner_kernel(float* __restrict__ out, int nj, int eqmode) {
  __shared__ double fact[66];
  int tid = threadIdx.x;
  if (tid < 66) { double f = 1.0; for (int i = 2; i <= tid; ++i) f *= (double)i; fact[tid] = f; }
  __syncthreads();
  int total = nj * LL * NQ;
  int idx = blockIdx.x * blockDim.x + tid;
  if (idx >= total) return;
  int q = idx % NQ;
  int l = (idx / NQ) % LL;
  int j = idx / (NQ * LL);
  int mp = q / MM - MOFF;
  int m  = q % MM - MOFF;
  int amp = mp < 0 ? -mp : mp, am = m < 0 ? -m : m;
  float res = 0.f;
  if (amp <= l && am <= l) {
    double beta = eqmode ? (PI_D * 0.5) : (PI_D * (2 * j + 1) / 64.0);
    double c = cos(beta * 0.5), s = sin(beta * 0.5);
    double pref = sqrt(fact[l + mp] * fact[l - mp] * fact[l + m] * fact[l - m]);
    int k0 = max(0, m - mp), k1 = min(l + m, l - mp);
    double acc = 0.0;
    for (int k = k0; k <= k1; ++k) {
      double denom = fact[l + m - k] * fact[k] * fact[l - k - mp] * fact[k - m + mp];
      double term = dpow(c, 2 * l - 2 * k + m - mp) * dpow(s, 2 * k - m + mp) / denom;
      acc += ((mp - m + k) & 1) ? -term : term;
    }
    res = (float)(pref * acc);
  }
  out[idx] = res;
}

// dbT[j][l][n][m] = dbeta[j][l][m][n]
__global__ void transpose_d_kernel(const float* __restrict__ dbeta, float* __restrict__ dbT) {
  int idx = blockIdx.x * blockDim.x + threadIdx.x;
  if (idx >= NB * LL * NQ) return;
  int m = idx % MM;
  int n = (idx / MM) % MM;
  int jl = idx / NQ;
  dbT[idx] = dbeta[jl * NQ + m * MM + n];
}

// ---------------- layer 1 (S2 conv) ----------------

__global__ __launch_bounds__(256) void s2_xh_kernel(const float* __restrict__ x,
                                                    const float* __restrict__ qw,
                                                    const float* __restrict__ dbeta,
                                                    float2* __restrict__ xh1) {
  __shared__ float xt[NB * NB];
  __shared__ float2 Xf0[NB * MM];
  __shared__ float2 tw[32];
  fill_tw(tw);
  int tid = threadIdx.x, b = blockIdx.x;
  for (int e = tid; e < NB * NB; e += 256) xt[e] = x[b * 1024 + e];
  __syncthreads();
  for (int e = tid; e < NB * MM; e += 256) {
    int j = e / MM, mi = e % MM, m = mi - MOFF;
    float re = 0.f, im = 0.f;
    const float* row = xt + j * NB;
    for (int a = 0; a < NB; ++a) {
      float v = row[a];
      float2 t = tw[(m * a) & 31];
      re += v * t.x; im -= v * t.y;   // e^{-i m a th}
    }
    Xf0[e] = c_mk(re, im);
  }
  __syncthreads();
  for (int e = tid; e < LL * MM; e += 256) {
    int l = e / MM, mi = e % MM;
    float re = 0.f, im = 0.f;
    for (int j = 0; j < NB; ++j) {
      float w = qw[j] * dbeta[(j * LL + l) * NQ + mi * MM + MOFF];
      float2 X = Xf0[j * MM + mi];
      re += w * X.x; im += w * X.y;
    }
    xh1[(b * LL + l) * MM + mi] = c_mk(re, im);
  }
}

// Wf[ni][ic] = sum_t W[ic][t] e^{-2pi i n t/32}, ic = i*Co+o
__global__ __launch_bounds__(256) void wfft_kernel(const float* __restrict__ W, int CiCo,
                                                   float2* __restrict__ Wf) {
  __shared__ float2 tw[32];
  fill_tw(tw);
  __syncthreads();
  int idx = blockIdx.x * blockDim.x + threadIdx.x;
  if (idx >= MM * CiCo) return;
  int ni = idx / CiCo, ic = idx % CiCo;
  int n = ni - MOFF;
  float re = 0.f, im = 0.f;
  for (int t = 0; t < NB; ++t) {
    float v = W[ic * NB + t];
    float2 tt = tw[(n * t) & 31];
    re += v * tt.x; im -= v * tt.y;
  }
  Wf[idx] = c_mk(re, im);
}

// z layout: [b][o][l][ni][mi].  z = deq0[l,ni] * xh1[b,l,mi] * conj(Wf1[ni,o])
__global__ void s2_z_kernel(const float2* __restrict__ xh1, const float2* __restrict__ Wf1,
                            const float* __restrict__ deq, float2* __restrict__ z) {
  int idx = blockIdx.x * blockDim.x + threadIdx.x;
  if (idx >= NBATCH * NCH * LL * NQ) return;
  int mi = idx % MM; int t = idx / MM;
  int ni = t % MM; t /= MM;
  int l = t % LL; t /= LL;
  int o = t % NCH; int b = t / NCH;
  float d0 = deq[(l * MM + ni) * MM + MOFF];
  float2 xv = xh1[(b * LL + l) * MM + mi];
  float2 wv = Wf1[ni * NCH + o];
  float re = d0 * (xv.x * wv.x + xv.y * wv.y);
  float im = d0 * (xv.y * wv.x - xv.x * wv.y);
  z[idx] = c_mk(re, im);
}

// ---------------- SO(3) inverse transform: split into fjq + dft ----------------

// F[bo][j][q] = sum_l (2l+1) * d^l_{m,n}(beta_j) * z[bo][l][q], q = ni*31+mi.
__global__ __launch_bounds__(256) void fjq_kernel(const float2* __restrict__ z,
                                                  const float* __restrict__ dbT,
                                                  float2* __restrict__ F) {
  __shared__ float2 zs[2][LL][8];
  int qg = blockIdx.x % 121;
  int bg = blockIdx.x / 121;
  int tid = threadIdx.x;
  int j = tid >> 3, ql = tid & 7;
  int q = qg * 8 + ql;
  bool qok = q < NQ;
  int qc = qok ? q : NQ - 1;
  float w[LL];
  #pragma unroll
  for (int l = 0; l < LL; ++l)
    w[l] = (2.f * l + 1.f) * dbT[(j * LL + l) * NQ + qc];
  int bo0 = bg * 25;
  if (tid < 128) {
    int l = tid >> 3, qq = qg * 8 + (tid & 7);
    int dd = (qq < NQ) ? (qq / MM - MOFF) : 99; if (dd < 0) dd = -dd;
    zs[0][l][tid & 7] = (l >= dd) ? z[((long long)bo0 * LL + l) * NQ + qq] : c_mk(0.f, 0.f);
  }
  __syncthreads();
  for (int i = 0; i < 25; ++i) {
    int bo = bo0 + i;
    if (i < 24 && tid < 128) {
      int l = tid >> 3, qq = qg * 8 + (tid & 7);
      int dd = (qq < NQ) ? (qq / MM - MOFF) : 99; if (dd < 0) dd = -dd;
      zs[(i + 1) & 1][l][tid & 7] =
          (l >= dd) ? z[((long long)(bo + 1) * LL + l) * NQ + qq] : c_mk(0.f, 0.f);
    }
    float fr = 0.f, fi = 0.f;
    #pragma unroll
    for (int l = 0; l < LL; ++l) {
      float2 zv = zs[i & 1][l][ql];
      fr += w[l] * zv.x; fi += w[l] * zv.y;
    }
    if (qok) F[((long long)bo * NB + j) * NQ + q] = c_mk(fr, fi);
    __syncthreads();
  }
}

// 2 tiles per 64-thread block. Direct coalesced register loads of F, register
// radix-2 FFTs, single-plane LDS transpose -> 8.7KB LDS.
__global__ __launch_bounds__(64) void so3_dft_kernel(const float2* __restrict__ F,
                                                     const float* __restrict__ bias,
                                                     float* __restrict__ out,
                                                     float2* __restrict__ parts) {
  __shared__ float S[2][32][33];
  __shared__ float2 tw[32];
  fill_tw(tw);
  int tid = threadIdx.x;
  int lane = tid & 31;
  int t = tid >> 5;                 // tile within block
  int idx = blockIdx.x * 2 + t;     // global tile
  int j = idx & 31;
  int bo = idx >> 5;                // same for both tiles (2 | 32)
  int o = bo % NCH;
  __syncthreads();                  // tw ready

  float vr[32], vi[32];

  // direct register load: lane = km; mi = (lane+15)&31 (lane 16 -> bin 16 = 0)
  int mi = (lane + 15) & 31;
  const float2* src = F + ((long long)bo * NB + j) * NQ + mi;
  bool mok = mi < MM;
  #pragma unroll
  for (int kn = 0; kn < 32; ++kn) {
    const int ni = (kn + 15) & 31;
    if (ni < MM) {
      float2 v = mok ? src[ni * MM] : c_mk(0.f, 0.f);
      vr[kn] = v.x; vi[kn] = v.y;
    } else { vr[kn] = 0.f; vi[kn] = 0.f; }
  }

  // ---- dim0 FFT over kn (registers), +i sign
  #pragma unroll
  for (int st = 0; st < 5; ++st) {
    const int half = 16 >> st, tmul = 1 << st;
    #pragma unroll
    for (int p = 0; p < 16; ++p) {
      const int j2 = p & (half - 1);
      const int i0 = ((p >> (4 - st)) << (5 - st)) + j2;
      const int i1 = i0 + half;
      float2 tt = tw[(j2 * tmul) & 31];
      float ur = vr[i0], ui = vi[i0], wr = vr[i1], wi = vi[i1];
      float dr = ur - wr, di = ui - wi;
      vr[i0] = ur + wr; vi[i0] = ui + wi;
      vr[i1] = dr * tt.x - di * tt.y;
      vi[i1] = dr * tt.y + di * tt.x;
    }
  }

  // ---- transpose via single plane: re, then im
  #pragma unroll
  for (int g = 0; g < 32; ++g) S[t][g][lane] = vr[bitrev5(g)];
  __syncthreads();
  #pragma unroll
  for (int k = 0; k < 32; ++k) vr[k] = S[t][lane][k];
  __syncthreads();
  #pragma unroll
  for (int g = 0; g < 32; ++g) S[t][g][lane] = vi[bitrev5(g)];
  __syncthreads();
  #pragma unroll
  for (int k = 0; k < 32; ++k) vi[k] = S[t][lane][k];

  // ---- dim1 FFT over km (registers), +i sign; lane = g now
  #pragma unroll
  for (int st = 0; st < 5; ++st) {
    const int half = 16 >> st, tmul = 1 << st;
    #pragma unroll
    for (int p = 0; p < 16; ++p) {
      const int j2 = p & (half - 1);
      const int i0 = ((p >> (4 - st)) << (5 - st)) + j2;
      const int i1 = i0 + half;
      float2 tt = tw[(j2 * tmul) & 31];
      float ur = vr[i0], ui = vi[i0], wr = vr[i1], wi = vi[i1];
      float dr = ur - wr, di = ui - wi;
      vr[i0] = ur + wr; vi[i0] = ui + wi;
      vr[i1] = dr * tt.x - di * tt.y;
      vi[i1] = dr * tt.y + di * tt.x;
    }
  }

  // ---- store out[a,g] = Re X[a] + bias (g = lane, coalesced); fused bn stats
  float bval = bias[o];
  long long obase = (long long)bo * SPAT + (long long)j * 1024 + lane;
  float s1 = 0.f, s2 = 0.f;
  #pragma unroll
  for (int a = 0; a < 32; ++a) {
    float val = vr[bitrev5(a)] + bval;
    out[obase + a * 32] = val;
    s1 += val; s2 += val * val;
  }
  #pragma unroll
  for (int off = 32; off > 0; off >>= 1) {
    s1 += __shfl_down(s1, off);
    s2 += __shfl_down(s2, off);
  }
  if (tid == 0) {
    atomicAdd(&parts[bo].x, s1);
    atomicAdd(&parts[bo].y, s2);
  }
}

// ---------------- batchnorm ----------------

__global__ void bn_finalize_kernel(const float2* __restrict__ partials,
                                   const float* __restrict__ g, const float* __restrict__ bb,
                                   float2* __restrict__ sc) {
  int o = threadIdx.x;
  if (o >= NCH) return;
  float s = 0.f, ss = 0.f;
  for (int b = 0; b < NBATCH; ++b) { float2 p = partials[b * NCH + o]; s += p.x; ss += p.y; }
  float inv = 1.f / (float)(NBATCH * SPAT);
  float mu = s * inv;
  float var = ss * inv - mu * mu;
  float scale = g[o] * rsqrtf(var + 1e-5f);
  sc[o] = c_mk(scale, bb[o] - mu * scale);
}

// ---------------- SO(3) conv ----------------

// Forward 2D FFT of a real 32x32 tile; 2 tiles per 64-thread block.
__global__ __launch_bounds__(64) void dft2f_kernel(const float* __restrict__ h,
                                                   const float2* __restrict__ sc,
                                                   float2* __restrict__ Xf) {
  __shared__ float S[2][32][33];
  __shared__ float2 tw[32];
  fill_tw(tw);
  int tid = threadIdx.x;
  int lane = tid & 31;
  int t = tid >> 5;
  long long idx = blockIdx.x * 2 + t;
  int c = (int)((idx >> 5) % NCH);
  float2 s = sc[c];
  __syncthreads();                  // tw ready

  float vr[32], vi[32];

  // lane = a row: load 32 consecutive floats (L1-friendly), bn+relu
  const float4* hp = reinterpret_cast<const float4*>(h + idx * 1024 + lane * 32);
  #pragma unroll
  for (int q4 = 0; q4 < 8; ++q4) {
    float4 v = hp[q4];
    vr[q4 * 4 + 0] = fmaxf(v.x * s.x + s.y, 0.f);
    vr[q4 * 4 + 1] = fmaxf(v.y * s.x + s.y, 0.f);
    vr[q4 * 4 + 2] = fmaxf(v.z * s.x + s.y, 0.f);
    vr[q4 * 4 + 3] = fmaxf(v.w * s.x + s.y, 0.f);
    vi[q4 * 4 + 0] = 0.f; vi[q4 * 4 + 1] = 0.f;
    vi[q4 * 4 + 2] = 0.f; vi[q4 * 4 + 3] = 0.f;
  }

  // ---- FFT over g (registers), conj twiddles (e^{-i})
  #pragma unroll
  for (int st = 0; st < 5; ++st) {
    const int half = 16 >> st, tmul = 1 << st;
    #pragma unroll
    for (int p = 0; p < 16; ++p) {
      const int j2 = p & (half - 1);
      const int i0 = ((p >> (4 - st)) << (5 - st)) + j2;
      const int i1 = i0 + half;
      float2 tt = tw[(j2 * tmul) & 31];
      float ur = vr[i0], ui = vi[i0], wr = vr[i1], wi = vi[i1];
      float dr = ur - wr, di = ui - wi;
      vr[i0] = ur + wr; vi[i0] = ui + wi;
      vr[i1] = dr * tt.x + di * tt.y;     // conj twiddle
      vi[i1] = di * tt.x - dr * tt.y;
    }
  }

  // ---- transpose via single plane: re, then im (un-bit-reversed rows)
  #pragma unroll
  for (int k = 0; k < 32; ++k) S[t][k][lane] = vr[bitrev5(k)];
  __syncthreads();
  #pragma unroll
  for (int a = 0; a < 32; ++a) vr[a] = S[t][lane][a];
  __syncthreads();
  #pragma unroll
  for (int k = 0; k < 32; ++k) S[t][k][lane] = vi[bitrev5(k)];
  __syncthreads();
  #pragma unroll
  for (int a = 0; a < 32; ++a) vi[a] = S[t][lane][a];

  // ---- FFT over a (registers), conj twiddles; lane = k_n now
  #pragma unroll
  for (int st = 0; st < 5; ++st) {
    const int half = 16 >> st, tmul = 1 << st;
    #pragma unroll
    for (int p = 0; p < 16; ++p) {
      const int j2 = p & (half - 1);
      const int i0 = ((p >> (4 - st)) << (5 - st)) + j2;
      const int i1 = i0 + half;
      float2 tt = tw[(j2 * tmul) & 31];
      float ur = vr[i0], ui = vi[i0], wr = vr[i1], wi = vi[i1];
      float dr = ur - wr, di = ui - wi;
      vr[i0] = ur + wr; vi[i0] = ui + wi;
      vr[i1] = dr * tt.x + di * tt.y;
      vi[i1] = di * tt.x - dr * tt.y;
    }
  }

  // ---- store: lane holds X[m, n] for all m at bin k_n = lane.
  int ni = (lane + 15) & 31;
  if (ni < MM) {
    float2* dst = Xf + idx * NQ + ni;
    #pragma unroll
    for (int mi = 0; mi < MM; ++mi) {
      const int km = (mi + 17) & 31;
      dst[mi * MM] = c_mk(vr[bitrev5(km)], vi[bitrev5(km)]);
    }
  }
}

// xh[bc,l,q] = sum_j qw[j]*dbeta[j,l,q]*Xf[bc,j,q]   (q = mi*MM+ni)
// Stores only supported l (l >= max(|mi-15|,|ni-15|)).
__global__ void xh_kernel(const float2* __restrict__ Xf, const float* __restrict__ qw,
                          const float* __restrict__ dbeta, float2* __restrict__ xh) {
  int idx = blockIdx.x * blockDim.x + threadIdx.x;
  if (idx >= NBATCH * NCH * NQ) return;
  int q = idx % NQ;
  int bc = idx / NQ;
  int dm = q / MM - MOFF; if (dm < 0) dm = -dm;
  int dn = q % MM - MOFF; if (dn < 0) dn = -dn;
  int lmin = dm > dn ? dm : dn;
  float2 acc[LL];
  #pragma unroll
  for (int l = 0; l < LL; ++l) acc[l] = c_mk(0.f, 0.f);
  for (int j = 0; j < NB; ++j) {
    float2 xv = Xf[((long long)bc * NB + j) * NQ + q];
    float qj = qw[j];
    const float* dbase = dbeta + (long long)(j * LL) * NQ + q;
    #pragma unroll
    for (int l = 0; l < LL; ++l) {
      float w = qj * dbase[l * NQ];
      acc[l].x += w * xv.x;
      acc[l].y += w * xv.y;
    }
  }
  #pragma unroll
  for (int l = 0; l < LL; ++l)
    if (l >= lmin) xh[((long long)bc * LL + l) * NQ + q] = acc[l];
}

// hk2[r][ni][ich], r = (l*8+b)*31+mi (l-major). Support sparsity.
__global__ __launch_bounds__(64) void hk_kernel(const float2* __restrict__ xh,
                                                const float* __restrict__ deq,
                                                float2* __restrict__ hk2) {
  int r = blockIdx.x;                 // (l*8+b)*31 + mi
  int mi = r % MM;
  int lb = r / MM;                    // l*8 + b
  int b = lb & 7;
  int l = lb >> 3;
  int adm = mi - MOFF; adm = adm < 0 ? -adm : adm;
  if (adm > l) return;
  int ich = threadIdx.x;
  if (ich >= NCH) return;
  float2 row[MM];
  const float2* src = xh + ((long long)(b * NCH + ich) * LL + l) * NQ + mi * MM;
  #pragma unroll
  for (int k = 0; k < MM; ++k) row[k] = src[k];
  const float* dl = deq + l * NQ;
  long long obase = (long long)r * MM * NCH + ich;
  for (int ni = MOFF - l; ni <= MOFF + l; ++ni) {
    const float* dr = dl + ni * MM;
    float re = 0.f, im = 0.f;
    #pragma unroll
    for (int k = 0; k < MM; ++k) {
      float d = dr[k];
      re += d * row[k].x;
      im += d * row[k].y;
    }
    hk2[obase + (long long)ni * NCH] = c_mk(re, im);
  }
}

// z[b][o][l][ni][mi] = sum_i hk2[(r*31+ni)*50+i] * conj(Wf[ni,i,o]).
__global__ __launch_bounds__(256) void z_kernel(const float2* __restrict__ hk2,
                                                const float2* __restrict__ Wf,
                                                float2* __restrict__ z) {
  __shared__ float2 ws[NCH * NCH];   // 20 KB
  int blk = blockIdx.x;
  int ni = 0;
  for (;;) {
    int d = ni - MOFF; if (d < 0) d = -d;
    int nt = 32 - 2 * d;
    if (blk < nt) break;
    blk -= nt; ++ni;
  }
  int dmin = ni - MOFF; if (dmin < 0) dmin = -dmin;
  int tid = threadIdx.x;
  {
    const float4* s4 = reinterpret_cast<const float4*>(Wf + ni * (NCH * NCH));
    float4* d4 = reinterpret_cast<float4*>(ws);
    for (int e = tid; e < NCH * NCH / 2; e += 256) d4[e] = s4[e];
  }
  __syncthreads();
  if (tid >= 248) return;
  int r = dmin * 248 + blk * 124 + (tid % 124);
  int o0 = (tid / 124) * 25;
  int mi = r % MM;
  int rem = r / MM;                  // l*8 + b
  int b = rem & 7;
  int l = rem >> 3;

  const float4* h4 = reinterpret_cast<const float4*>(hk2 + ((long long)r * MM + ni) * NCH);

  float2 acc[25];
  #pragma unroll
  for (int u = 0; u < 25; ++u) acc[u] = c_mk(0.f, 0.f);

  for (int ih = 0; ih < 25; ++ih) {     // 2 channels per iteration
    float4 hv = h4[ih];
    const float2* w0 = ws + (2 * ih) * NCH + o0;
    #pragma unroll
    for (int u = 0; u < 25; ++u) {
      float2 w = w0[u];
      acc[u].x += hv.x * w.x + hv.y * w.y;
      acc[u].y += hv.y * w.x - hv.x * w.y;
    }
    const float2* w1 = w0 + NCH;
    #pragma unroll
    for (int u = 0; u < 25; ++u) {
      float2 w = w1[u];
      acc[u].x += hv.z * w.x + hv.w * w.y;
      acc[u].y += hv.w * w.x - hv.z * w.y;
    }
  }

  long long zbase = (((long long)(b * NCH + o0) * LL + l) * NQ) + ni * MM + mi;
  #pragma unroll
  for (int u = 0; u < 25; ++u)
    z[zbase + (long long)u * LL * NQ] = acc[u];
}

// ---------------- head ----------------

// pool with fused bn+relu (layer-3 scale/shift applied per element)
__global__ void pool_kernel(const float* __restrict__ h, const float2* __restrict__ sc,
                            float* __restrict__ pooled) {
  __shared__ float sm[256];
  int tid = threadIdx.x;
  int o = blockIdx.x % NCH;
  float2 s = sc[o];
  const float* base = h + (long long)blockIdx.x * SPAT;
  float best = -1e30f;
  for (int e = tid; e < 1024; e += 256) {
    float acc = 0.f;
    for (int g = 0; g < NB; ++g) {
      float v = base[e * NB + g];
      acc += fmaxf(v * s.x + s.y, 0.f);
    }
    best = fmaxf(best, acc * (1.f / 32.f));
  }
  sm[tid] = best;
  __syncthreads();
  for (int st = 128; st > 0; st >>= 1) {
    if (tid < st) sm[tid] = fmaxf(sm[tid], sm[tid + st]);
    __syncthreads();
  }
  if (tid == 0) pooled[blockIdx.x] = sm[0];
}

// fc1 + BN1 + relu. Thread = output o (8 blocks x 32).
__global__ __launch_bounds__(32) void fc1_kernel(const float* __restrict__ pooled,
    const float* __restrict__ fc1w, const float* __restrict__ fc1b,
    const float* __restrict__ g1, const float* __restrict__ b1,
    float* __restrict__ A) {
  int o = blockIdx.x * 32 + threadIdx.x;   // 0..255
  const float* wr = fc1w + o * NCH;
  float v[NBATCH];
  float bias = fc1b[o];
  #pragma unroll
  for (int b = 0; b < NBATCH; ++b) v[b] = bias;
  for (int c = 0; c < NCH; ++c) {
    float w = wr[c];
    #pragma unroll
    for (int b = 0; b < NBATCH; ++b) v[b] += pooled[b * NCH + c] * w;
  }
  float s = 0.f, ss = 0.f;
  #pragma unroll
  for (int b = 0; b < NBATCH; ++b) { s += v[b]; ss += v[b] * v[b]; }
  float mu = s * 0.125f, var = ss * 0.125f - mu * mu;
  float scl = g1[o] * rsqrtf(var + 1e-5f), sh = b1[o] - mu * scl;
  #pragma unroll
  for (int b = 0; b < NBATCH; ++b) A[b * 256 + o] = fmaxf(v[b] * scl + sh, 0.f);
}

// fc2 + BN2 + relu. 16 blocks x 64; thread = (o_local, b).
__global__ __launch_bounds__(64) void fc2_kernel(const float* __restrict__ A,
    const float* __restrict__ fc2w, const float* __restrict__ fc2b,
    const float* __restrict__ g2, const float* __restrict__ b2,
    float* __restrict__ A2) {
  int tid = threadIdx.x;
  int o = blockIdx.x * 8 + (tid >> 3);
  int b = tid & 7;
  const float4* av = reinterpret_cast<const float4*>(A + b * 256);
  const float4* wv = reinterpret_cast<const float4*>(fc2w + o * 256);
  float acc = fc2b[o];
  #pragma unroll
  for (int c4 = 0; c4 < 64; ++c4) {
    float4 a = av[c4], w = wv[c4];
    acc += a.x * w.x + a.y * w.y + a.z * w.z + a.w * w.w;
  }
  float s = acc, ss = acc * acc;
  #pragma unroll
  for (int m = 1; m < 8; m <<= 1) {
    s += __shfl_xor(s, m);
    ss += __shfl_xor(ss, m);
  }
  float mu = s * 0.125f, var = ss * 0.125f - mu * mu;
  float scl = g2[o] * rsqrtf(var + 1e-5f), sh = b2[o] - mu * scl;
  A2[b * 128 + o] = fmaxf(acc * scl + sh, 0.f);
}

// fc3 + log-softmax. One block per batch.
__global__ __launch_bounds__(64) void fc3_kernel(const float* __restrict__ A2,
    const float* __restrict__ fc3w, const float* __restrict__ fc3b,
    float* __restrict__ out) {
  __shared__ float Cm[40];
  int tid = threadIdx.x;
  int b = blockIdx.x;
  if (tid < 40) {
    const float* wr = fc3w + tid * 128;
    const float* ar = A2 + b * 128;
    float acc = fc3b[tid];
    #pragma unroll
    for (int c = 0; c < 128; ++c) acc += ar[c] * wr[c];
    Cm[tid] = acc;
  }
  __syncthreads();
  if (tid == 0) {
    float mx = -1e30f;
    for (int f = 0; f < 40; ++f) mx = fmaxf(mx, Cm[f]);
    float se = 0.f;
    for (int f = 0; f < 40; ++f) se += expf(Cm[f] - mx);
    float lse = mx + logf(se);
    for (int f = 0; f < 40; ++f) out[b * 40 + f] = Cm[f] - lse;
  }
}

// ---------------- host ----------------

extern "C" void kernel_launch(void* const* d_in, const int* in_sizes, int n_in,
                              void* d_out, int out_size, void* d_ws, size_t ws_size,
                              hipStream_t stream) {
  (void)in_sizes; (void)n_in; (void)out_size;
  const float* x    = (const float*)d_in[0];
  const float* k1   = (const float*)d_in[1];
  const float* c1b  = (const float*)d_in[2];
  const float* bn1g = (const float*)d_in[3];
  const float* bn1b = (const float*)d_in[4];
  const float* k2   = (const float*)d_in[5];
  const float* c2b  = (const float*)d_in[6];
  const float* bn2g = (const float*)d_in[7];
  const float* bn2b = (const float*)d_in[8];
  const float* k3   = (const float*)d_in[9];
  const float* c3b  = (const float*)d_in[10];
  const float* bn3g = (const float*)d_in[11];
  const float* bn3b = (const float*)d_in[12];
  const float* fc1w = (const float*)d_in[13];
  const float* fc1b = (const float*)d_in[14];
  const float* g1   = (const float*)d_in[15];
  const float* bb1  = (const float*)d_in[16];
  const float* fc2w = (const float*)d_in[17];
  const float* fc2b = (const float*)d_in[18];
  const float* g2   = (const float*)d_in[19];
  const float* bb2  = (const float*)d_in[20];
  const float* fc3w = (const float*)d_in[21];
  const float* fc3b = (const float*)d_in[22];
  float* out = (float*)d_out;

  char* ws = (char*)d_ws;
  size_t off = 0;
  auto alloc = [&](size_t n) -> char* {
    char* p = ws + off;
    off += (n + 255) & ~(size_t)255;
    return p;
  };

  float*  dbeta  = (float*)alloc(sizeof(float) * NB * LL * NQ);      // 1.97 MB
  float*  dbT    = (float*)alloc(sizeof(float) * NB * LL * NQ);      // 1.97 MB
  float*  deq    = (float*)alloc(sizeof(float) * LL * NQ);
  float*  qw     = (float*)alloc(sizeof(float) * NB);
  float2* xh1    = (float2*)alloc(sizeof(float2) * NBATCH * LL * MM);
  float2* Wf     = (float2*)alloc(sizeof(float2) * MM * NCH * NCH);  // 620 KB
  float2* parts  = (float2*)alloc(sizeof(float2) * NBATCH * NCH);
  float2* bnsc   = (float2*)alloc(sizeof(float2) * 64);
  float*  pooled = (float*)alloc(sizeof(float) * NBATCH * NCH);
  float*  Abuf   = (float*)alloc(sizeof(float) * NBATCH * 256);
  float*  A2buf  = (float*)alloc(sizeof(float) * NBATCH * 128);
  float*  HA     = (float*)alloc(sizeof(float) * (size_t)HN);        // 52.4 MB
  float*  HB     = (float*)alloc(sizeof(float) * (size_t)HN);        // 52.4 MB
  size_t XFB = (size_t)NBATCH * NCH * NB * NQ * sizeof(float2);      // 98.4 MB
  size_t XHB = (size_t)NBATCH * NCH * LL * NQ * sizeof(float2);      // 49.2 MB
  char* AR = alloc(XFB + XHB);                                       // 147.6 MB arena
  float2* Xf  = (float2*)AR;           // live: dft2 -> xh
  float2* xh  = (float2*)(AR + XFB);   // live: xh -> hk
  float2* hk2 = (float2*)AR;           // live: hk -> z    (reuses dead Xf)
  float2* zb  = (float2*)(AR + XFB);   // live: z -> fjq   (reuses dead xh; also z1)
  float2* Fb  = (float2*)AR;           // live: fjq -> dft (reuses dead hk2/Xf; 98.4 MB exact)

  if (ws_size < off) return;  // insufficient scratch: leave d_out zeroed

  const int T = 256;
  const size_t PARTS_B = sizeof(float2) * NBATCH * NCH;
  // constants
  qw_kernel<<<1, 32, 0, stream>>>(qw);
  wigner_kernel<<<(NB * LL * NQ + T - 1) / T, T, 0, stream>>>(dbeta, NB, 0);
  wigner_kernel<<<(LL * NQ + T - 1) / T, T, 0, stream>>>(deq, 1, 1);
  transpose_d_kernel<<<(NB * LL * NQ + T - 1) / T, T, 0, stream>>>(dbeta, dbT);

  // ---- layer 1: S2 conv -> HA
  s2_xh_kernel<<<NBATCH, T, 0, stream>>>(x, qw, dbeta, xh1);
  wfft_kernel<<<(MM * 1 * NCH + T - 1) / T, T, 0, stream>>>(k1, 1 * NCH, Wf);
  s2_z_kernel<<<(NBATCH * NCH * LL * NQ + T - 1) / T, T, 0, stream>>>(xh1, Wf, deq, zb);
  fjq_kernel<<<121 * 16, T, 0, stream>>>(zb, dbT, Fb);
  hipMemsetAsync(parts, 0, PARTS_B, stream);
  so3_dft_kernel<<<NBATCH * NCH * NB / 2, 64, 0, stream>>>(Fb, c1b, HA, parts);
  bn_finalize_kernel<<<1, 64, 0, stream>>>(parts, bn1g, bn1b, bnsc);

  // ---- layer 2: SO(3) conv HA -> HB (bn1+relu fused into dft2f load)
  dft2f_kernel<<<NBATCH * NCH * NB / 2, 64, 0, stream>>>(HA, bnsc, Xf);
  xh_kernel<<<(NBATCH * NCH * NQ + T - 1) / T, T, 0, stream>>>(Xf, qw, dbeta, xh);
  wfft_kernel<<<(MM * NCH * NCH + T - 1) / T, T, 0, stream>>>(k2, NCH * NCH, Wf);
  hk_kernel<<<NBATCH * LL * MM, 64, 0, stream>>>(xh, deq, hk2);
  z_kernel<<<512, T, 0, stream>>>(hk2, Wf, zb);
  fjq_kernel<<<121 * 16, T, 0, stream>>>(zb, dbT, Fb);
  hipMemsetAsync(parts, 0, PARTS_B, stream);
  so3_dft_kernel<<<NBATCH * NCH * NB / 2, 64, 0, stream>>>(Fb, c2b, HB, parts);
  bn_finalize_kernel<<<1, 64, 0, stream>>>(parts, bn2g, bn2b, bnsc);

  // ---- layer 3: SO(3) conv HB -> HA (bn2+relu fused into dft2f load)
  dft2f_kernel<<<NBATCH * NCH * NB / 2, 64, 0, stream>>>(HB, bnsc, Xf);
  xh_kernel<<<(NBATCH * NCH * NQ + T - 1) / T, T, 0, stream>>>(Xf, qw, dbeta, xh);
  wfft_kernel<<<(MM * NCH * NCH + T - 1) / T, T, 0, stream>>>(k3, NCH * NCH, Wf);
  hk_kernel<<<NBATCH * LL * MM, 64, 0, stream>>>(xh, deq, hk2);
  z_kernel<<<512, T, 0, stream>>>(hk2, Wf, zb);
  fjq_kernel<<<121 * 16, T, 0, stream>>>(zb, dbT, Fb);
  hipMemsetAsync(parts, 0, PARTS_B, stream);
  so3_dft_kernel<<<NBATCH * NCH * NB / 2, 64, 0, stream>>>(Fb, c3b, HA, parts);
  bn_finalize_kernel<<<1, 64, 0, stream>>>(parts, bn3g, bn3b, bnsc);

  // ---- head: pool (bn3+relu fused) + split FC stack
  pool_kernel<<<NBATCH * NCH, T, 0, stream>>>(HA, bnsc, pooled);
  fc1_kernel<<<8, 32, 0, stream>>>(pooled, fc1w, fc1b, g1, bb1, Abuf);
  fc2_kernel<<<16, 64, 0, stream>>>(Abuf, fc2w, fc2b, g2, bb2, A2buf);
  fc3_kernel<<<8, 64, 0, stream>>>(A2buf, fc3w, fc3b, out);
}

// Round 19
// 672.092 us; speedup vs baseline: 1.2645x; 1.0140x over previous
//
#include <hip/hip_runtime.h>
#include <math.h>

constexpr int NB = 32;       // samples per angle
constexpr int LL = 16;       // bandwidth
constexpr int MM = 31;       // spectral orders (2*BW-1)
constexpr int MOFF = 15;
constexpr int NBATCH = 8;
constexpr int NCH = 50;
constexpr int NQ = MM * MM;          // 961
constexpr int SPAT = NB * NB * NB;   // 32768
constexpr long long HN = (long long)NBATCH * NCH * SPAT;  // 13,107,200

#define PI_D 3.14159265358979323846

__device__ inline float2 c_mk(float x, float y) { float2 r; r.x = x; r.y = y; return r; }

__device__ inline void fill_tw(float2* tw) {
  int t = threadIdx.x;
  if (t < 32) {
    double a = (double)t * (PI_D / 16.0);
    tw[t] = c_mk((float)cos(a), (float)sin(a));
  }
}

__device__ inline int bitrev5(int n) {
  return ((n & 1) << 4) | ((n & 2) << 2) | (n & 4) | ((n & 8) >> 2) | ((n & 16) >> 4);
}

__device__ inline double dpow(double x, int n) {
  double r = 1.0;
  for (int i = 0; i < n; ++i) r *= x;
  return r;
}

// ---------------- constants ----------------

__global__ void qw_kernel(float* __restrict__ qw) {
  int j = threadIdx.x;
  if (j >= NB) return;
  double beta = PI_D * (2 * j + 1) / 64.0;
  double acc = 0.0;
  for (int kk = 0; kk < LL; ++kk)
    acc += sin((double)(2 * j + 1) * (2 * kk + 1) * PI_D / 64.0) / (double)(2 * kk + 1);
  qw[j] = (float)((2.0 / 16.0) * sin(beta) * acc);
}

// out layout [j][l][mp][m]; eqmode: nj==1, beta=pi/2
__global__ void wigner_kernel(float* __restrict__ out, int nj, int eqmode) {
  __shared__ double fact[66];
  int tid = threadIdx.x;
  if (tid < 66) { double f = 1.0; for (int i = 2; i <= tid; ++i) f *= (double)i; fact[tid] = f; }
  __syncthreads();
  int total = nj * LL * NQ;
  int idx = blockIdx.x * blockDim.x + tid;
  if (idx >= total) return;
  int q = idx % NQ;
  int l = (idx / NQ) % LL;
  int j = idx / (NQ * LL);
  int mp = q / MM - MOFF;
  int m  = q % MM - MOFF;
  int amp = mp < 0 ? -mp : mp, am = m < 0 ? -m : m;
  float res = 0.f;
  if (amp <= l && am <= l) {
    double beta = eqmode ? (PI_D * 0.5) : (PI_D * (2 * j + 1) / 64.0);
    double c = cos(beta * 0.5), s = sin(beta * 0.5);
    double pref = sqrt(fact[l + mp] * fact[l - mp] * fact[l + m] * fact[l - m]);
    int k0 = max(0, m - mp), k1 = min(l + m, l - mp);
    double acc = 0.0;
    for (int k = k0; k <= k1; ++k) {
      double denom = fact[l + m - k] * fact[k] * fact[l - k - mp] * fact[k - m + mp];
      double term = dpow(c, 2 * l - 2 * k + m - mp) * dpow(s, 2 * k - m + mp) / denom;
      acc += ((mp - m + k) & 1) ? -term : term;
    }
    res = (float)(pref * acc);
  }
  out[idx] = res;
}

// dbT[j][l][n][m] = dbeta[j][l][m][n]
__global__ void transpose_d_kernel(const float* __restrict__ dbeta, float* __restrict__ dbT) {
  int idx = blockIdx.x * blockDim.x + threadIdx.x;
  if (idx >= NB * LL * NQ) return;
  int m = idx % MM;
  int n = (idx / MM) % MM;
  int jl = idx / NQ;
  dbT[idx] = dbeta[jl * NQ + m * MM + n];
}

// ---------------- layer 1 (S2 conv) ----------------

__global__ __launch_bounds__(256) void s2_xh_kernel(const float* __restrict__ x,
                                                    const float* __restrict__ qw,
                                                    const float* __restrict__ dbeta,
                                                    float2* __restrict__ xh1) {
  __shared__ float xt[NB * NB];
  __shared__ float2 Xf0[NB * MM];
  __shared__ float2 tw[32];
  fill_tw(tw);
  int tid = threadIdx.x, b = blockIdx.x;
  for (int e = tid; e < NB * NB; e += 256) xt[e] = x[b * 1024 + e];
  __syncthreads();
  for (int e = tid; e < NB * MM; e += 256) {
    int j = e / MM, mi = e % MM, m = mi - MOFF;
    float re = 0.f, im = 0.f;
    const float* row = xt + j * NB;
    for (int a = 0; a < NB; ++a) {
      float v = row[a];
      float2 t = tw[(m * a) & 31];
      re += v * t.x; im -= v * t.y;   // e^{-i m a th}
    }
    Xf0[e] = c_mk(re, im);
  }
  __syncthreads();
  for (int e = tid; e < LL * MM; e += 256) {
    int l = e / MM, mi = e % MM;
    float re = 0.f, im = 0.f;
    for (int j = 0; j < NB; ++j) {
      float w = qw[j] * dbeta[(j * LL + l) * NQ + mi * MM + MOFF];
      float2 X = Xf0[j * MM + mi];
      re += w * X.x; im += w * X.y;
    }
    xh1[(b * LL + l) * MM + mi] = c_mk(re, im);
  }
}

// Wf[ni][ic] = sum_t W[ic][t] e^{-2pi i n t/32}, ic = i*Co+o
__global__ __launch_bounds__(256) void wfft_kernel(const float* __restrict__ W, int CiCo,
                                                   float2* __restrict__ Wf) {
  __shared__ float2 tw[32];
  fill_tw(tw);
  __syncthreads();
  int idx = blockIdx.x * blockDim.x + threadIdx.x;
  if (idx >= MM * CiCo) return;
  int ni = idx / CiCo, ic = idx % CiCo;
  int n = ni - MOFF;
  float re = 0.f, im = 0.f;
  for (int t = 0; t < NB; ++t) {
    float v = W[ic * NB + t];
    float2 tt = tw[(n * t) & 31];
    re += v * tt.x; im -= v * tt.y;
  }
  Wf[idx] = c_mk(re, im);
}

// z layout: [b][o][l][ni][mi].  z = deq0[l,ni] * xh1[b,l,mi] * conj(Wf1[ni,o])
__global__ void s2_z_kernel(const float2* __restrict__ xh1, const float2* __restrict__ Wf1,
                            const float* __restrict__ deq, float2* __restrict__ z) {
  int idx = blockIdx.x * blockDim.x + threadIdx.x;
  if (idx >= NBATCH * NCH * LL * NQ) return;
  int mi = idx % MM; int t = idx / MM;
  int ni = t % MM; t /= MM;
  int l = t % LL; t /= LL;
  int o = t % NCH; int b = t / NCH;
  float d0 = deq[(l * MM + ni) * MM + MOFF];
  float2 xv = xh1[(b * LL + l) * MM + mi];
  float2 wv = Wf1[ni * NCH + o];
  float re = d0 * (xv.x * wv.x + xv.y * wv.y);
  float im = d0 * (xv.y * wv.x - xv.x * wv.y);
  z[idx] = c_mk(re, im);
}

// ---------------- SO(3) inverse transform: split into fjq + dft ----------------

// F[bo][j][q] = sum_l (2l+1) * d^l_{m,n}(beta_j) * z[bo][l][q], q = ni*31+mi.
__global__ __launch_bounds__(256) void fjq_kernel(const float2* __restrict__ z,
                                                  const float* __restrict__ dbT,
                                                  float2* __restrict__ F) {
  __shared__ float2 zs[2][LL][8];
  int qg = blockIdx.x % 121;
  int bg = blockIdx.x / 121;
  int tid = threadIdx.x;
  int j = tid >> 3, ql = tid & 7;
  int q = qg * 8 + ql;
  bool qok = q < NQ;
  int qc = qok ? q : NQ - 1;
  float w[LL];
  #pragma unroll
  for (int l = 0; l < LL; ++l)
    w[l] = (2.f * l + 1.f) * dbT[(j * LL + l) * NQ + qc];
  int bo0 = bg * 25;
  if (tid < 128) {
    int l = tid >> 3, qq = qg * 8 + (tid & 7);
    int dd = (qq < NQ) ? (qq / MM - MOFF) : 99; if (dd < 0) dd = -dd;
    zs[0][l][tid & 7] = (l >= dd) ? z[((long long)bo0 * LL + l) * NQ + qq] : c_mk(0.f, 0.f);
  }
  __syncthreads();
  for (int i = 0; i < 25; ++i) {
    int bo = bo0 + i;
    if (i < 24 && tid < 128) {
      int l = tid >> 3, qq = qg * 8 + (tid & 7);
      int dd = (qq < NQ) ? (qq / MM - MOFF) : 99; if (dd < 0) dd = -dd;
      zs[(i + 1) & 1][l][tid & 7] =
          (l >= dd) ? z[((long long)(bo + 1) * LL + l) * NQ + qq] : c_mk(0.f, 0.f);
    }
    float fr = 0.f, fi = 0.f;
    #pragma unroll
    for (int l = 0; l < LL; ++l) {
      float2 zv = zs[i & 1][l][ql];
      fr += w[l] * zv.x; fi += w[l] * zv.y;
    }
    if (qok) F[((long long)bo * NB + j) * NQ + q] = c_mk(fr, fi);
    __syncthreads();
  }
}

// 2 tiles per 64-thread block. Direct coalesced register loads of F, register
// radix-2 FFTs, single-plane LDS transpose -> 8.7KB LDS.
__global__ __launch_bounds__(64) void so3_dft_kernel(const float2* __restrict__ F,
                                                     const float* __restrict__ bias,
                                                     float* __restrict__ out,
                                                     float2* __restrict__ parts) {
  __shared__ float S[2][32][33];
  __shared__ float2 tw[32];
  fill_tw(tw);
  int tid = threadIdx.x;
  int lane = tid & 31;
  int t = tid >> 5;                 // tile within block
  int idx = blockIdx.x * 2 + t;     // global tile
  int j = idx & 31;
  int bo = idx >> 5;                // same for both tiles (2 | 32)
  int o = bo % NCH;
  __syncthreads();                  // tw ready

  float vr[32], vi[32];

  // direct register load: lane = km; mi = (lane+15)&31 (lane 16 -> bin 16 = 0)
  int mi = (lane + 15) & 31;
  const float2* src = F + ((long long)bo * NB + j) * NQ + mi;
  bool mok = mi < MM;
  #pragma unroll
  for (int kn = 0; kn < 32; ++kn) {
    const int ni = (kn + 15) & 31;
    if (ni < MM) {
      float2 v = mok ? src[ni * MM] : c_mk(0.f, 0.f);
      vr[kn] = v.x; vi[kn] = v.y;
    } else { vr[kn] = 0.f; vi[kn] = 0.f; }
  }

  // ---- dim0 FFT over kn (registers), +i sign
  #pragma unroll
  for (int st = 0; st < 5; ++st) {
    const int half = 16 >> st, tmul = 1 << st;
    #pragma unroll
    for (int p = 0; p < 16; ++p) {
      const int j2 = p & (half - 1);
      const int i0 = ((p >> (4 - st)) << (5 - st)) + j2;
      const int i1 = i0 + half;
      float2 tt = tw[(j2 * tmul) & 31];
      float ur = vr[i0], ui = vi[i0], wr = vr[i1], wi = vi[i1];
      float dr = ur - wr, di = ui - wi;
      vr[i0] = ur + wr; vi[i0] = ui + wi;
      vr[i1] = dr * tt.x - di * tt.y;
      vi[i1] = dr * tt.y + di * tt.x;
    }
  }

  // ---- transpose via single plane: re, then im
  #pragma unroll
  for (int g = 0; g < 32; ++g) S[t][g][lane] = vr[bitrev5(g)];
  __syncthreads();
  #pragma unroll
  for (int k = 0; k < 32; ++k) vr[k] = S[t][lane][k];
  __syncthreads();
  #pragma unroll
  for (int g = 0; g < 32; ++g) S[t][g][lane] = vi[bitrev5(g)];
  __syncthreads();
  #pragma unroll
  for (int k = 0; k < 32; ++k) vi[k] = S[t][lane][k];

  // ---- dim1 FFT over km (registers), +i sign; lane = g now
  #pragma unroll
  for (int st = 0; st < 5; ++st) {
    const int half = 16 >> st, tmul = 1 << st;
    #pragma unroll
    for (int p = 0; p < 16; ++p) {
      const int j2 = p & (half - 1);
      const int i0 = ((p >> (4 - st)) << (5 - st)) + j2;
      const int i1 = i0 + half;
      float2 tt = tw[(j2 * tmul) & 31];
      float ur = vr[i0], ui = vi[i0], wr = vr[i1], wi = vi[i1];
      float dr = ur - wr, di = ui - wi;
      vr[i0] = ur + wr; vi[i0] = ui + wi;
      vr[i1] = dr * tt.x - di * tt.y;
      vi[i1] = dr * tt.y + di * tt.x;
    }
  }

  // ---- store out[a,g] = Re X[a] + bias (g = lane, coalesced); fused bn stats
  float bval = bias[o];
  long long obase = (long long)bo * SPAT + (long long)j * 1024 + lane;
  float s1 = 0.f, s2 = 0.f;
  #pragma unroll
  for (int a = 0; a < 32; ++a) {
    float val = vr[bitrev5(a)] + bval;
    out[obase + a * 32] = val;
    s1 += val; s2 += val * val;
  }
  #pragma unroll
  for (int off = 32; off > 0; off >>= 1) {
    s1 += __shfl_down(s1, off);
    s2 += __shfl_down(s2, off);
  }
  if (tid == 0) {
    atomicAdd(&parts[bo].x, s1);
    atomicAdd(&parts[bo].y, s2);
  }
}

// ---------------- batchnorm ----------------

__global__ void bn_finalize_kernel(const float2* __restrict__ partials,
                                   const float* __restrict__ g, const float* __restrict__ bb,
                                   float2* __restrict__ sc) {
  int o = threadIdx.x;
  if (o >= NCH) return;
  float s = 0.f, ss = 0.f;
  for (int b = 0; b < NBATCH; ++b) { float2 p = partials[b * NCH + o]; s += p.x; ss += p.y; }
  float inv = 1.f / (float)(NBATCH * SPAT);
  float mu = s * inv;
  float var = ss * inv - mu * mu;
  float scale = g[o] * rsqrtf(var + 1e-5f);
  sc[o] = c_mk(scale, bb[o] - mu * scale);
}

// ---------------- SO(3) conv ----------------

// Forward 2D FFT of a real 32x32 tile; 2 tiles per 64-thread block.
__global__ __launch_bounds__(64) void dft2f_kernel(const float* __restrict__ h,
                                                   const float2* __restrict__ sc,
                                                   float2* __restrict__ Xf) {
  __shared__ float S[2][32][33];
  __shared__ float2 tw[32];
  fill_tw(tw);
  int tid = threadIdx.x;
  int lane = tid & 31;
  int t = tid >> 5;
  long long idx = blockIdx.x * 2 + t;
  int c = (int)((idx >> 5) % NCH);
  float2 s = sc[c];
  __syncthreads();                  // tw ready

  float vr[32], vi[32];

  // lane = a row: load 32 consecutive floats (L1-friendly), bn+relu
  const float4* hp = reinterpret_cast<const float4*>(h + idx * 1024 + lane * 32);
  #pragma unroll
  for (int q4 = 0; q4 < 8; ++q4) {
    float4 v = hp[q4];
    vr[q4 * 4 + 0] = fmaxf(v.x * s.x + s.y, 0.f);
    vr[q4 * 4 + 1] = fmaxf(v.y * s.x + s.y, 0.f);
    vr[q4 * 4 + 2] = fmaxf(v.z * s.x + s.y, 0.f);
    vr[q4 * 4 + 3] = fmaxf(v.w * s.x + s.y, 0.f);
    vi[q4 * 4 + 0] = 0.f; vi[q4 * 4 + 1] = 0.f;
    vi[q4 * 4 + 2] = 0.f; vi[q4 * 4 + 3] = 0.f;
  }

  // ---- FFT over g (registers), conj twiddles (e^{-i})
  #pragma unroll
  for (int st = 0; st < 5; ++st) {
    const int half = 16 >> st, tmul = 1 << st;
    #pragma unroll
    for (int p = 0; p < 16; ++p) {
      const int j2 = p & (half - 1);
      const int i0 = ((p >> (4 - st)) << (5 - st)) + j2;
      const int i1 = i0 + half;
      float2 tt = tw[(j2 * tmul) & 31];
      float ur = vr[i0], ui = vi[i0], wr = vr[i1], wi = vi[i1];
      float dr = ur - wr, di = ui - wi;
      vr[i0] = ur + wr; vi[i0] = ui + wi;
      vr[i1] = dr * tt.x + di * tt.y;     // conj twiddle
      vi[i1] = di * tt.x - dr * tt.y;
    }
  }

  // ---- transpose via single plane: re, then im (un-bit-reversed rows)
  #pragma unroll
  for (int k = 0; k < 32; ++k) S[t][k][lane] = vr[bitrev5(k)];
  __syncthreads();
  #pragma unroll
  for (int a = 0; a < 32; ++a) vr[a] = S[t][lane][a];
  __syncthreads();
  #pragma unroll
  for (int k = 0; k < 32; ++k) S[t][k][lane] = vi[bitrev5(k)];
  __syncthreads();
  #pragma unroll
  for (int a = 0; a < 32; ++a) vi[a] = S[t][lane][a];

  // ---- FFT over a (registers), conj twiddles; lane = k_n now
  #pragma unroll
  for (int st = 0; st < 5; ++st) {
    const int half = 16 >> st, tmul = 1 << st;
    #pragma unroll
    for (int p = 0; p < 16; ++p) {
      const int j2 = p & (half - 1);
      const int i0 = ((p >> (4 - st)) << (5 - st)) + j2;
      const int i1 = i0 + half;
      float2 tt = tw[(j2 * tmul) & 31];
      float ur = vr[i0], ui = vi[i0], wr = vr[i1], wi = vi[i1];
      float dr = ur - wr, di = ui - wi;
      vr[i0] = ur + wr; vi[i0] = ui + wi;
      vr[i1] = dr * tt.x + di * tt.y;
      vi[i1] = di * tt.x - dr * tt.y;
    }
  }

  // ---- store: lane holds X[m, n] for all m at bin k_n = lane.
  int ni = (lane + 15) & 31;
  if (ni < MM) {
    float2* dst = Xf + idx * NQ + ni;
    #pragma unroll
    for (int mi = 0; mi < MM; ++mi) {
      const int km = (mi + 17) & 31;
      dst[mi * MM] = c_mk(vr[bitrev5(km)], vi[bitrev5(km)]);
    }
  }
}

// xh[bc,l,q] = sum_j qw[j]*dbeta[j,l,q]*Xf[bc,j,q]   (q = mi*MM+ni)
// Stores only supported l (l >= max(|mi-15|,|ni-15|)).
__global__ void xh_kernel(const float2* __restrict__ Xf, const float* __restrict__ qw,
                          const float* __restrict__ dbeta, float2* __restrict__ xh) {
  int idx = blockIdx.x * blockDim.x + threadIdx.x;
  if (idx >= NBATCH * NCH * NQ) return;
  int q = idx % NQ;
  int bc = idx / NQ;
  int dm = q / MM - MOFF; if (dm < 0) dm = -dm;
  int dn = q % MM - MOFF; if (dn < 0) dn = -dn;
  int lmin = dm > dn ? dm : dn;
  float2 acc[LL];
  #pragma unroll
  for (int l = 0; l < LL; ++l) acc[l] = c_mk(0.f, 0.f);
  for (int j = 0; j < NB; ++j) {
    float2 xv = Xf[((long long)bc * NB + j) * NQ + q];
    float qj = qw[j];
    const float* dbase = dbeta + (long long)(j * LL) * NQ + q;
    #pragma unroll
    for (int l = 0; l < LL; ++l) {
      float w = qj * dbase[l * NQ];
      acc[l].x += w * xv.x;
      acc[l].y += w * xv.y;
    }
  }
  #pragma unroll
  for (int l = 0; l < LL; ++l)
    if (l >= lmin) xh[((long long)bc * LL + l) * NQ + q] = acc[l];
}

// hk2[r][ni][ich], r = (l*8+b)*31+mi (l-major). Support sparsity.
__global__ __launch_bounds__(64) void hk_kernel(const float2* __restrict__ xh,
                                                const float* __restrict__ deq,
                                                float2* __restrict__ hk2) {
  int r = blockIdx.x;                 // (l*8+b)*31 + mi
  int mi = r % MM;
  int lb = r / MM;                    // l*8 + b
  int b = lb & 7;
  int l = lb >> 3;
  int adm = mi - MOFF; adm = adm < 0 ? -adm : adm;
  if (adm > l) return;
  int ich = threadIdx.x;
  if (ich >= NCH) return;
  float2 row[MM];
  const float2* src = xh + ((long long)(b * NCH + ich) * LL + l) * NQ + mi * MM;
  #pragma unroll
  for (int k = 0; k < MM; ++k) row[k] = src[k];
  const float* dl = deq + l * NQ;
  long long obase = (long long)r * MM * NCH + ich;
  for (int ni = MOFF - l; ni <= MOFF + l; ++ni) {
    const float* dr = dl + ni * MM;
    float re = 0.f, im = 0.f;
    #pragma unroll
    for (int k = 0; k < MM; ++k) {
      float d = dr[k];
      re += d * row[k].x;
      im += d * row[k].y;
    }
    hk2[obase + (long long)ni * NCH] = c_mk(re, im);
  }
}

// z[b][o][l][ni][mi] = sum_i hk2[(r*31+ni)*50+i] * conj(Wf[ni,i,o]).
// 4 o-quarters (13/13/12/12) x 62 rows per 256-thread block -> 1024 blocks,
// ~2x the waves of the 2-half version (z was latency-bound at 17% occupancy).
__global__ __launch_bounds__(256) void z_kernel(const float2* __restrict__ hk2,
                                                const float2* __restrict__ Wf,
                                                float2* __restrict__ z) {
  __shared__ float2 ws[NCH * NCH + 64];   // padded: oq=3 lane-13 dummy read stays in-bounds
  int blk = blockIdx.x;
  int ni = 0;
  for (;;) {
    int d = ni - MOFF; if (d < 0) d = -d;
    int nt = 4 * (16 - d);
    if (blk < nt) break;
    blk -= nt; ++ni;
  }
  int dmin = ni - MOFF; if (dmin < 0) dmin = -dmin;
  int tid = threadIdx.x;
  {
    const float4* s4 = reinterpret_cast<const float4*>(Wf + ni * (NCH * NCH));
    float4* d4 = reinterpret_cast<float4*>(ws);
    for (int e = tid; e < NCH * NCH / 2; e += 256) d4[e] = s4[e];
  }
  __syncthreads();
  if (tid >= 248) return;
  int rl = tid % 62;
  int oq = tid / 62;                       // 0..3
  int o0 = 13 * oq - (oq == 3 ? 1 : 0);    // 0,13,26,38
  int no = (oq < 2) ? 13 : 12;
  int r = dmin * 248 + blk * 62 + rl;
  int mi = r % MM;
  int rem = r / MM;                        // l*8 + b
  int b = rem & 7;
  int l = rem >> 3;

  const float4* h4 = reinterpret_cast<const float4*>(hk2 + ((long long)r * MM + ni) * NCH);

  float2 acc[13];
  #pragma unroll
  for (int u = 0; u < 13; ++u) acc[u] = c_mk(0.f, 0.f);

  for (int ih = 0; ih < 25; ++ih) {     // 2 channels per iteration
    float4 hv = h4[ih];
    const float2* w0 = ws + (2 * ih) * NCH + o0;
    #pragma unroll
    for (int u = 0; u < 13; ++u) {
      float2 w = w0[u];
      acc[u].x += hv.x * w.x + hv.y * w.y;
      acc[u].y += hv.y * w.x - hv.x * w.y;
    }
    const float2* w1 = w0 + NCH;
    #pragma unroll
    for (int u = 0; u < 13; ++u) {
      float2 w = w1[u];
      acc[u].x += hv.z * w.x + hv.w * w.y;
      acc[u].y += hv.w * w.x - hv.z * w.y;
    }
  }

  long long zbase = (((long long)(b * NCH + o0) * LL + l) * NQ) + ni * MM + mi;
  #pragma unroll
  for (int u = 0; u < 13; ++u)
    if (u < no) z[zbase + (long long)u * LL * NQ] = acc[u];
}

// ---------------- head ----------------

// pool with fused bn+relu (layer-3 scale/shift applied per element)
__global__ void pool_kernel(const float* __restrict__ h, const float2* __restrict__ sc,
                            float* __restrict__ pooled) {
  __shared__ float sm[256];
  int tid = threadIdx.x;
  int o = blockIdx.x % NCH;
  float2 s = sc[o];
  const float* base = h + (long long)blockIdx.x * SPAT;
  float best = -1e30f;
  for (int e = tid; e < 1024; e += 256) {
    float acc = 0.f;
    for (int g = 0; g < NB; ++g) {
      float v = base[e * NB + g];
      acc += fmaxf(v * s.x + s.y, 0.f);
    }
    best = fmaxf(best, acc * (1.f / 32.f));
  }
  sm[tid] = best;
  __syncthreads();
  for (int st = 128; st > 0; st >>= 1) {
    if (tid < st) sm[tid] = fmaxf(sm[tid], sm[tid + st]);
    __syncthreads();
  }
  if (tid == 0) pooled[blockIdx.x] = sm[0];
}

// fc1 + BN1 + relu. Thread = output o (8 blocks x 32).
__global__ __launch_bounds__(32) void fc1_kernel(const float* __restrict__ pooled,
    const float* __restrict__ fc1w, const float* __restrict__ fc1b,
    const float* __restrict__ g1, const float* __restrict__ b1,
    float* __restrict__ A) {
  int o = blockIdx.x * 32 + threadIdx.x;   // 0..255
  const float* wr = fc1w + o * NCH;
  float v[NBATCH];
  float bias = fc1b[o];
  #pragma unroll
  for (int b = 0; b < NBATCH; ++b) v[b] = bias;
  for (int c = 0; c < NCH; ++c) {
    float w = wr[c];
    #pragma unroll
    for (int b = 0; b < NBATCH; ++b) v[b] += pooled[b * NCH + c] * w;
  }
  float s = 0.f, ss = 0.f;
  #pragma unroll
  for (int b = 0; b < NBATCH; ++b) { s += v[b]; ss += v[b] * v[b]; }
  float mu = s * 0.125f, var = ss * 0.125f - mu * mu;
  float scl = g1[o] * rsqrtf(var + 1e-5f), sh = b1[o] - mu * scl;
  #pragma unroll
  for (int b = 0; b < NBATCH; ++b) A[b * 256 + o] = fmaxf(v[b] * scl + sh, 0.f);
}

// fc2 + BN2 + relu. 16 blocks x 64; thread = (o_local, b).
__global__ __launch_bounds__(64) void fc2_kernel(const float* __restrict__ A,
    const float* __restrict__ fc2w, const float* __restrict__ fc2b,
    const float* __restrict__ g2, const float* __restrict__ b2,
    float* __restrict__ A2) {
  int tid = threadIdx.x;
  int o = blockIdx.x * 8 + (tid >> 3);
  int b = tid & 7;
  const float4* av = reinterpret_cast<const float4*>(A + b * 256);
  const float4* wv = reinterpret_cast<const float4*>(fc2w + o * 256);
  float acc = fc2b[o];
  #pragma unroll
  for (int c4 = 0; c4 < 64; ++c4) {
    float4 a = av[c4], w = wv[c4];
    acc += a.x * w.x + a.y * w.y + a.z * w.z + a.w * w.w;
  }
  float s = acc, ss = acc * acc;
  #pragma unroll
  for (int m = 1; m < 8; m <<= 1) {
    s += __shfl_xor(s, m);
    ss += __shfl_xor(ss, m);
  }
  float mu = s * 0.125f, var = ss * 0.125f - mu * mu;
  float scl = g2[o] * rsqrtf(var + 1e-5f), sh = b2[o] - mu * scl;
  A2[b * 128 + o] = fmaxf(acc * scl + sh, 0.f);
}

// fc3 + log-softmax. One block per batch.
__global__ __launch_bounds__(64) void fc3_kernel(const float* __restrict__ A2,
    const float* __restrict__ fc3w, const float* __restrict__ fc3b,
    float* __restrict__ out) {
  __shared__ float Cm[40];
  int tid = threadIdx.x;
  int b = blockIdx.x;
  if (tid < 40) {
    const float* wr = fc3w + tid * 128;
    const float* ar = A2 + b * 128;
    float acc = fc3b[tid];
    #pragma unroll
    for (int c = 0; c < 128; ++c) acc += ar[c] * wr[c];
    Cm[tid] = acc;
  }
  __syncthreads();
  if (tid == 0) {
    float mx = -1e30f;
    for (int f = 0; f < 40; ++f) mx = fmaxf(mx, Cm[f]);
    float se = 0.f;
    for (int f = 0; f < 40; ++f) se += expf(Cm[f] - mx);
    float lse = mx + logf(se);
    for (int f = 0; f < 40; ++f) out[b * 40 + f] = Cm[f] - lse;
  }
}

// ---------------- host ----------------

extern "C" void kernel_launch(void* const* d_in, const int* in_sizes, int n_in,
                              void* d_out, int out_size, void* d_ws, size_t ws_size,
                              hipStream_t stream) {
  (void)in_sizes; (void)n_in; (void)out_size;
  const float* x    = (const float*)d_in[0];
  const float* k1   = (const float*)d_in[1];
  const float* c1b  = (const float*)d_in[2];
  const float* bn1g = (const float*)d_in[3];
  const float* bn1b = (const float*)d_in[4];
  const float* k2   = (const float*)d_in[5];
  const float* c2b  = (const float*)d_in[6];
  const float* bn2g = (const float*)d_in[7];
  const float* bn2b = (const float*)d_in[8];
  const float* k3   = (const float*)d_in[9];
  const float* c3b  = (const float*)d_in[10];
  const float* bn3g = (const float*)d_in[11];
  const float* bn3b = (const float*)d_in[12];
  const float* fc1w = (const float*)d_in[13];
  const float* fc1b = (const float*)d_in[14];
  const float* g1   = (const float*)d_in[15];
  const float* bb1  = (const float*)d_in[16];
  const float* fc2w = (const float*)d_in[17];
  const float* fc2b = (const float*)d_in[18];
  const float* g2   = (const float*)d_in[19];
  const float* bb2  = (const float*)d_in[20];
  const float* fc3w = (const float*)d_in[21];
  const float* fc3b = (const float*)d_in[22];
  float* out = (float*)d_out;

  char* ws = (char*)d_ws;
  size_t off = 0;
  auto alloc = [&](size_t n) -> char* {
    char* p = ws + off;
    off += (n + 255) & ~(size_t)255;
    return p;
  };

  float*  dbeta  = (float*)alloc(sizeof(float) * NB * LL * NQ);      // 1.97 MB
  float*  dbT    = (float*)alloc(sizeof(float) * NB * LL * NQ);      // 1.97 MB
  float*  deq    = (float*)alloc(sizeof(float) * LL * NQ);
  float*  qw     = (float*)alloc(sizeof(float) * NB);
  float2* xh1    = (float2*)alloc(sizeof(float2) * NBATCH * LL * MM);
  float2* Wf     = (float2*)alloc(sizeof(float2) * MM * NCH * NCH);  // 620 KB
  float2* parts  = (float2*)alloc(sizeof(float2) * NBATCH * NCH);
  float2* bnsc   = (float2*)alloc(sizeof(float2) * 64);
  float*  pooled = (float*)alloc(sizeof(float) * NBATCH * NCH);
  float*  Abuf   = (float*)alloc(sizeof(float) * NBATCH * 256);
  float*  A2buf  = (float*)alloc(sizeof(float) * NBATCH * 128);
  float*  HA     = (float*)alloc(sizeof(float) * (size_t)HN);        // 52.4 MB
  float*  HB     = (float*)alloc(sizeof(float) * (size_t)HN);        // 52.4 MB
  size_t XFB = (size_t)NBATCH * NCH * NB * NQ * sizeof(float2);      // 98.4 MB
  size_t XHB = (size_t)NBATCH * NCH * LL * NQ * sizeof(float2);      // 49.2 MB
  char* AR = alloc(XFB + XHB);                                       // 147.6 MB arena
  float2* Xf  = (float2*)AR;           // live: dft2 -> xh
  float2* xh  = (float2*)(AR + XFB);   // live: xh -> hk
  float2* hk2 = (float2*)AR;           // live: hk -> z    (reuses dead Xf)
  float2* zb  = (float2*)(AR + XFB);   // live: z -> fjq   (reuses dead xh; also z1)
  float2* Fb  = (float2*)AR;           // live: fjq -> dft (reuses dead hk2/Xf; 98.4 MB exact)

  if (ws_size < off) return;  // insufficient scratch: leave d_out zeroed

  const int T = 256;
  const size_t PARTS_B = sizeof(float2) * NBATCH * NCH;
  // constants
  qw_kernel<<<1, 32, 0, stream>>>(qw);
  wigner_kernel<<<(NB * LL * NQ + T - 1) / T, T, 0, stream>>>(dbeta, NB, 0);
  wigner_kernel<<<(LL * NQ + T - 1) / T, T, 0, stream>>>(deq, 1, 1);
  transpose_d_kernel<<<(NB * LL * NQ + T - 1) / T, T, 0, stream>>>(dbeta, dbT);

  // ---- layer 1: S2 conv -> HA
  s2_xh_kernel<<<NBATCH, T, 0, stream>>>(x, qw, dbeta, xh1);
  wfft_kernel<<<(MM * 1 * NCH + T - 1) / T, T, 0, stream>>>(k1, 1 * NCH, Wf);
  s2_z_kernel<<<(NBATCH * NCH * LL * NQ + T - 1) / T, T, 0, stream>>>(xh1, Wf, deq, zb);
  fjq_kernel<<<121 * 16, T, 0, stream>>>(zb, dbT, Fb);
  hipMemsetAsync(parts, 0, PARTS_B, stream);
  so3_dft_kernel<<<NBATCH * NCH * NB / 2, 64, 0, stream>>>(Fb, c1b, HA, parts);
  bn_finalize_kernel<<<1, 64, 0, stream>>>(parts, bn1g, bn1b, bnsc);

  // ---- layer 2: SO(3) conv HA -> HB (bn1+relu fused into dft2f load)
  dft2f_kernel<<<NBATCH * NCH * NB / 2, 64, 0, stream>>>(HA, bnsc, Xf);
  xh_kernel<<<(NBATCH * NCH * NQ + T - 1) / T, T, 0, stream>>>(Xf, qw, dbeta, xh);
  wfft_kernel<<<(MM * NCH * NCH + T - 1) / T, T, 0, stream>>>(k2, NCH * NCH, Wf);
  hk_kernel<<<NBATCH * LL * MM, 64, 0, stream>>>(xh, deq, hk2);
  z_kernel<<<1024, T, 0, stream>>>(hk2, Wf, zb);
  fjq_kernel<<<121 * 16, T, 0, stream>>>(zb, dbT, Fb);
  hipMemsetAsync(parts, 0, PARTS_B, stream);
  so3_dft_kernel<<<NBATCH * NCH * NB / 2, 64, 0, stream>>>(Fb, c2b, HB, parts);
  bn_finalize_kernel<<<1, 64, 0, stream>>>(parts, bn2g, bn2b, bnsc);

  // ---- layer 3: SO(3) conv HB -> HA (bn2+relu fused into dft2f load)
  dft2f_kernel<<<NBATCH * NCH * NB / 2, 64, 0, stream>>>(HB, bnsc, Xf);
  xh_kernel<<<(NBATCH * NCH * NQ + T - 1) / T, T, 0, stream>>>(Xf, qw, dbeta, xh);
  wfft_kernel<<<(MM * NCH * NCH + T - 1) / T, T, 0, stream>>>(k3, NCH * NCH, Wf);
  hk_kernel<<<NBATCH * LL * MM, 64, 0, stream>>>(xh, deq, hk2);
  z_kernel<<<1024, T, 0, stream>>>(hk2, Wf, zb);
  fjq_kernel<<<121 * 16, T, 0, stream>>>(zb, dbT, Fb);
  hipMemsetAsync(parts, 0, PARTS_B, stream);
  so3_dft_kernel<<<NBATCH * NCH * NB / 2, 64, 0, stream>>>(Fb, c3b, HA, parts);
  bn_finalize_kernel<<<1, 64, 0, stream>>>(parts, bn3g, bn3b, bnsc);

  // ---- head: pool (bn3+relu fused) + split FC stack
  pool_kernel<<<NBATCH * NCH, T, 0, stream>>>(HA, bnsc, pooled);
  fc1_kernel<<<8, 32, 0, stream>>>(pooled, fc1w, fc1b, g1, bb1, Abuf);
  fc2_kernel<<<16, 64, 0, stream>>>(Abuf, fc2w, fc2b, g2, bb2, A2buf);
  fc3_kernel<<<8, 64, 0, stream>>>(A2buf, fc3w, fc3b, out);
}